// Round 1
// baseline (1629.027 us; speedup 1.0000x reference)
//
#include <hip/hip_runtime.h>
#include <math.h>

#define KSZ  3
#define PADC 1
#define CIN  64
#define COUT 128
#define IH   64
#define IW   64
#define NB   16
#define OYX  129
#define NOFF 18
#define SPO  (OYX * OYX)   // 16641
#define BNEPS 1e-5f

// ---------------- weight pre-transpose ----------------
// w_def_t[kk][c][o]  = w_def[o][c][kk]      (9*64*128)
// w_up_t[ky*3+kx][co][ci] = w_up[ci][co][ky][kx]  (9*128*128)
__global__ void k_prep(const float* __restrict__ w_def, const float* __restrict__ w_up,
                       float* __restrict__ w_def_t, float* __restrict__ w_up_t)
{
    int idx = blockIdx.x * 256 + threadIdx.x;
    if (idx < 9 * CIN * COUT) {
        const int o  = idx & 127;
        const int c  = (idx >> 7) & 63;
        const int kk = idx >> 13;
        w_def_t[idx] = w_def[(o * CIN + c) * 9 + kk];
    }
    idx -= 9 * CIN * COUT;
    if (idx >= 0 && idx < 9 * COUT * COUT) {
        const int ci = idx & 127;
        const int co = (idx >> 7) & 127;
        const int kk = idx >> 14;
        w_up_t[idx] = w_up[(ci * COUT + co) * 9 + kk];
    }
}

// ---------------- offset conv (3x3, 64->18, pad 1) ----------------
__global__ __launch_bounds__(256) void k_offset_conv(
    const float* __restrict__ x, const float* __restrict__ w_off,
    const float* __restrict__ b_off, float* __restrict__ offs)
{
    const int idx = blockIdx.x * 256 + threadIdx.x;  // NB*NOFF*IH*IW
    const int w  = idx & 63;
    const int h  = (idx >> 6) & 63;
    const int oc = (idx >> 12) % NOFF;
    const int b  = idx / (NOFF * IH * IW);

    float acc = b_off[oc];
    const float* wp = w_off + oc * CIN * 9;
    const float* xb = x + b * (CIN * IH * IW);
    for (int ci = 0; ci < CIN; ++ci) {
        const float* plane = xb + ci * (IH * IW);
        const float* wc = wp + ci * 9;
        #pragma unroll
        for (int ki = 0; ki < 3; ++ki) {
            const int yy = h - PADC + ki;
            if (yy < 0 || yy >= IH) continue;
            const float* rowp = plane + yy * IW;
            #pragma unroll
            for (int kj = 0; kj < 3; ++kj) {
                const int xx = w - PADC + kj;
                if (xx < 0 || xx >= IW) continue;
                acc += rowp[xx] * wc[ki * 3 + kj];
            }
        }
    }
    offs[idx] = acc;
}

// ---------------- deformable conv ----------------
// block = (b, h0=2 rows). Writes feats channel-last: feats_t[b][h][w][o]
__global__ __launch_bounds__(256) void k_deform(
    const float* __restrict__ x, const float* __restrict__ offs,
    const float* __restrict__ w_def_t, const float* __restrict__ b_def,
    float* __restrict__ feats_t)
{
    __shared__ float s_s[2][CIN][64];    // [row][c][w]      32 KB
    __shared__ float s_wk[CIN][COUT];    // [c][o]           32 KB
    __shared__ int   s_ci[2][4][64];     // corner idx (SoA)  2 KB
    __shared__ float s_cw[2][4][64];     // corner wgt        2 KB

    const int tid = threadIdx.x;
    const int b   = blockIdx.x >> 5;
    const int h0  = (blockIdx.x & 31) << 1;
    const int row = tid >> 7;            // 0..1
    const int ot  = (tid & 127) >> 3;    // 0..15 -> o tile of 8
    const int wt  = tid & 7;             // 0..7  -> w tile of 8
    const int o0  = ot * 8;
    const int w0  = wt * 8;

    const float* xb = x + b * (CIN * IH * IW);

    float acc[8][8] = {};

    for (int kk = 0; kk < 9; ++kk) {
        __syncthreads();
        // stage per-kk weights [c][o]
        {
            const float4* src = (const float4*)(w_def_t + kk * (CIN * COUT));
            float4* dst = (float4*)&s_wk[0][0];
            #pragma unroll
            for (int i = 0; i < 8; ++i) dst[tid + i * 256] = src[tid + i * 256];
        }
        // per-pixel bilinear corner data
        if (tid < 128) {
            const int r = tid >> 6, w = tid & 63;
            const int h = h0 + r;
            const int ki = kk / 3, kj = kk - ki * 3;
            const float dy = offs[((b * NOFF + kk * 2) * IH + h) * IW + w];
            const float dx = offs[((b * NOFF + kk * 2 + 1) * IH + h) * IW + w];
            const float py = (float)(h - PADC + ki) + dy;
            const float px = (float)(w - PADC + kj) + dx;
            const float y0f = floorf(py), x0f = floorf(px);
            const float ly = py - y0f, lx = px - x0f;
            const int y0 = (int)y0f, x0 = (int)x0f;
            const float wy[2] = {1.f - ly, ly};
            const float wx[2] = {1.f - lx, lx};
            #pragma unroll
            for (int cy = 0; cy < 2; ++cy)
                #pragma unroll
                for (int cx = 0; cx < 2; ++cx) {
                    const int yy = y0 + cy, xx = x0 + cx;
                    const bool v = (yy >= 0) & (yy < IH) & (xx >= 0) & (xx < IW);
                    s_ci[r][cy * 2 + cx][w] = v ? (yy * IW + xx) : -1;
                    s_cw[r][cy * 2 + cx][w] = wy[cy] * wx[cx];
                }
        }
        __syncthreads();
        // bilinear sampling into s_s: 8192 samples
        #pragma unroll 4
        for (int it = 0; it < 32; ++it) {
            const int i = tid + it * 256;
            const int w = i & 63, c = (i >> 6) & 63, r = i >> 12;
            const float* plane = xb + c * (IH * IW);
            float v = 0.f;
            #pragma unroll
            for (int cp = 0; cp < 4; ++cp) {
                const int   ii = s_ci[r][cp][w];
                const float cw = s_cw[r][cp][w];
                if (ii >= 0) v += plane[ii] * cw;
            }
            s_s[r][c][w] = v;
        }
        __syncthreads();
        // register-tiled GEMM: acc[o][w] += sum_c s[c][w] * wk[c][o]
        for (int c = 0; c < CIN; ++c) {
            const float4* sp4 = (const float4*)&s_s[row][c][0];
            const float4 sa = sp4[wt * 2], sb = sp4[wt * 2 + 1];
            const float4* wp4 = (const float4*)&s_wk[c][0];
            const float4 wa = wp4[ot * 2], wb = wp4[ot * 2 + 1];
            const float sv[8] = {sa.x, sa.y, sa.z, sa.w, sb.x, sb.y, sb.z, sb.w};
            const float wv[8] = {wa.x, wa.y, wa.z, wa.w, wb.x, wb.y, wb.z, wb.w};
            #pragma unroll
            for (int j = 0; j < 8; ++j)
                #pragma unroll
                for (int p = 0; p < 8; ++p)
                    acc[j][p] += wv[j] * sv[p];
        }
    }
    // epilogue: bias + store channel-last
    const int h = h0 + row;
    float bd[8];
    #pragma unroll
    for (int j = 0; j < 8; ++j) bd[j] = b_def[o0 + j];
    #pragma unroll
    for (int p = 0; p < 8; ++p) {
        float* dst = feats_t + ((b * IH + h) * IW + (w0 + p)) * COUT + o0;
        float4 v0 = {acc[0][p] + bd[0], acc[1][p] + bd[1], acc[2][p] + bd[2], acc[3][p] + bd[3]};
        float4 v1 = {acc[4][p] + bd[4], acc[5][p] + bd[5], acc[6][p] + bd[6], acc[7][p] + bd[7]};
        ((float4*)dst)[0] = v0;
        ((float4*)dst)[1] = v1;
    }
}

// ---------------- conv transpose (stride 2), ox in [0,128) ----------------
// block = (b, oy, co-half of 64). y layout [b][co][oy][ox], unnormalized.
__global__ __launch_bounds__(256) void k_convT(
    const float* __restrict__ feats_t, const float* __restrict__ w_up_t,
    const float* __restrict__ b_up, float* __restrict__ y)
{
    __shared__ float s_f[2][65][COUT];   // XOR-swizzled quads; row 64 = zeros

    const int tid = threadIdx.x;
    const int blk = blockIdx.x;
    const int ch  = blk & 1;
    const int t2  = blk >> 1;
    const int oy  = t2 % OYX;
    const int b   = t2 / OYX;
    const int cg  = tid >> 5;     // 0..7
    const int oxs = tid & 31;     // thread covers ox = oxs*4 + 0..3
    const int co0 = ch * 64 + cg * 8;

    int nky = 0; int kyr[2]; int iyr[2];
    #pragma unroll
    for (int ky = 0; ky < 3; ++ky) {
        const int t = oy - ky;
        if (t >= 0 && (t & 1) == 0 && (t >> 1) < IH) { kyr[nky] = ky; iyr[nky] = t >> 1; ++nky; }
    }
    for (int r = 0; r < nky; ++r) {
        const float4* src = (const float4*)(feats_t + ((b * IH + iyr[r]) * IW) * COUT);
        for (int i = tid; i < 2048; i += 256) {
            const int ix = i >> 5, cq = i & 31;
            ((float4*)&s_f[r][ix][0])[cq ^ (ix & 7)] = src[i];
        }
        if (tid < 128) s_f[r][64][tid] = 0.f;  // zero row for invalid taps
    }
    __syncthreads();

    float acc[8][4] = {};
    for (int r = 0; r < nky; ++r) {
        const int ky = kyr[r];
        #pragma unroll
        for (int kx = 0; kx < 3; ++kx) {
            const int pa = kx & 1;                    // valid p parities: pa, pa+2
            int ixa = (oxs * 4 + pa - kx) >> 1;
            const int ixb = ixa + 1;
            if (ixa < 0) ixa = 64;                    // -> zero row
            const float4* fa = (const float4*)&s_f[r][ixa][0];
            const float4* fb = (const float4*)&s_f[r][ixb][0];
            const int sa = ixa & 7, sb = ixb & 7;
            const float4* wrow = (const float4*)(w_up_t + ((ky * 3 + kx) * COUT + co0) * COUT);
            #pragma unroll 4
            for (int cq = 0; cq < 32; ++cq) {
                const float4 f0 = fa[cq ^ sa];
                const float4 f1 = fb[cq ^ sb];
                #pragma unroll
                for (int j = 0; j < 8; ++j) {
                    const float4 wv = wrow[j * 32 + cq];
                    acc[j][pa]     += wv.x * f0.x + wv.y * f0.y + wv.z * f0.z + wv.w * f0.w;
                    acc[j][pa + 2] += wv.x * f1.x + wv.y * f1.y + wv.z * f1.z + wv.w * f1.w;
                }
            }
        }
    }
    #pragma unroll
    for (int j = 0; j < 8; ++j) {
        const int co = co0 + j;
        const float bias = b_up[co];
        float* dst = y + ((b * COUT + co) * OYX + oy) * OYX + oxs * 4;
        #pragma unroll
        for (int p = 0; p < 4; ++p) dst[p] = acc[j][p] + bias;
    }
}

// ---------------- conv transpose edge column ox = 128 (kx=2, ix=63 only) ----------------
__global__ void k_convT_edge(
    const float* __restrict__ feats_t, const float* __restrict__ w_up_t,
    const float* __restrict__ b_up, float* __restrict__ y)
{
    const int idx = blockIdx.x * 256 + threadIdx.x;  // NB*COUT*OYX
    const int oy = idx % OYX;
    const int co = (idx / OYX) % COUT;
    const int b  = idx / (OYX * COUT);
    float acc = b_up[co];
    #pragma unroll
    for (int ky = 0; ky < 3; ++ky) {
        const int t = oy - ky;
        if (t >= 0 && (t & 1) == 0 && (t >> 1) < IH) {
            const int iy = t >> 1;
            const float4* f  = (const float4*)(feats_t + ((b * IH + iy) * IW + 63) * COUT);
            const float4* wv = (const float4*)(w_up_t + ((ky * 3 + 2) * COUT + co) * COUT);
            float s = 0.f;
            for (int cq = 0; cq < 32; ++cq) {
                const float4 a = f[cq], w = wv[cq];
                s += a.x * w.x + a.y * w.y + a.z * w.z + a.w * w.w;
            }
            acc += s;
        }
    }
    y[((b * COUT + co) * OYX + oy) * OYX + 128] = acc;
}

// ---------------- BN stats: one block per channel ----------------
__global__ __launch_bounds__(256) void k_bn_stats(const float* __restrict__ y, float* __restrict__ stats)
{
    const int c = blockIdx.x;
    const int tid = threadIdx.x;
    float s = 0.f, sq = 0.f;
    for (int i = tid; i < NB * SPO; i += 256) {
        const int b = i / SPO, sp = i - b * SPO;
        const float v = y[(b * COUT + c) * SPO + sp];
        s += v; sq += v * v;
    }
    __shared__ float rs[256], rq[256];
    rs[tid] = s; rq[tid] = sq;
    __syncthreads();
    for (int off = 128; off > 0; off >>= 1) {
        if (tid < off) { rs[tid] += rs[tid + off]; rq[tid] += rq[tid + off]; }
        __syncthreads();
    }
    if (tid == 0) {
        const float n = (float)(NB * SPO);
        const float mean = rs[0] / n;
        const float var  = rq[0] / n - mean * mean;
        stats[c] = mean;
        stats[COUT + c] = rsqrtf(var + BNEPS);
    }
}

// ---------------- BN apply + ReLU (in place on d_out) ----------------
__global__ void k_bn_apply(float* __restrict__ y, const float* __restrict__ stats,
                           const float* __restrict__ gamma, const float* __restrict__ beta)
{
    const int i = blockIdx.x * 256 + threadIdx.x;
    const int c = (i / SPO) & (COUT - 1);
    const float mean = stats[c], rstd = stats[COUT + c];
    float v = y[i];
    v = (v - mean) * rstd * gamma[c] + beta[c];
    y[i] = fmaxf(v, 0.f);
}

extern "C" void kernel_launch(void* const* d_in, const int* in_sizes, int n_in,
                              void* d_out, int out_size, void* d_ws, size_t ws_size,
                              hipStream_t stream)
{
    const float* x     = (const float*)d_in[0];
    const float* w_off = (const float*)d_in[1];
    const float* b_off = (const float*)d_in[2];
    const float* w_def = (const float*)d_in[3];
    const float* b_def = (const float*)d_in[4];
    const float* w_up  = (const float*)d_in[5];
    const float* b_up  = (const float*)d_in[6];
    const float* gamma = (const float*)d_in[7];
    const float* beta  = (const float*)d_in[8];
    float* y = (float*)d_out;

    float* ws      = (float*)d_ws;
    float* offs    = ws;                  // 1,179,648 floats
    float* feats_t = offs + 1179648;      // 8,388,608 floats
    float* w_def_t = feats_t + 8388608;   //    73,728 floats
    float* w_up_t  = w_def_t + 73728;     //   147,456 floats
    float* stats   = w_up_t + 147456;     //       256 floats

    k_prep       <<<dim3(864),    dim3(256), 0, stream>>>(w_def, w_up, w_def_t, w_up_t);
    k_offset_conv<<<dim3(4608),   dim3(256), 0, stream>>>(x, w_off, b_off, offs);
    k_deform     <<<dim3(512),    dim3(256), 0, stream>>>(x, offs, w_def_t, b_def, feats_t);
    k_convT      <<<dim3(4128),   dim3(256), 0, stream>>>(feats_t, w_up_t, b_up, y);
    k_convT_edge <<<dim3(1032),   dim3(256), 0, stream>>>(feats_t, w_up_t, b_up, y);
    k_bn_stats   <<<dim3(128),    dim3(256), 0, stream>>>(y, stats);
    k_bn_apply   <<<dim3(133128), dim3(256), 0, stream>>>(y, stats, gamma, beta);
}

// Round 2
// 1089.206 us; speedup vs baseline: 1.4956x; 1.4956x over previous
//
#include <hip/hip_runtime.h>
#include <math.h>

#define PADC 1
#define CIN  64
#define COUT 128
#define IH   64
#define IW   64
#define NB   16
#define OYX  129
#define NOFF 18
#define SPO  (OYX * OYX)   // 16641
#define BNEPS 1e-5f

typedef __attribute__((ext_vector_type(8))) short bf16x8;
typedef __attribute__((ext_vector_type(4))) float f32x4;

static __device__ __forceinline__ unsigned short f2bf(float f) {
    unsigned int b = __float_as_uint(f);
    unsigned int r = (b + 0x7FFFu + ((b >> 16) & 1u)) >> 16;   // RNE
    return (unsigned short)r;
}

// ---------------- weight prep ----------------
// w_def_t[kk][c][o] = w_def[o][c][kk]  (9*64*128 f32)
// WB: bf16 MFMA-B-fragment-ordered convT weights, 4 segments:
//   seg0 @0      : py=0 G0 (even ox), K=512: slot=k>>8 (0:ky=2,1:ky=0), kx=((k>>7)&1)?0:2, ci=k&127
//   seg1 @65536  : py=1 G0,           K=256: ky=1, kx=(k>>7)?0:2, ci=k&127
//   seg2 @98304  : py=0 G1 (odd ox),  K=256: slot=k>>7 (0:ky=2,1:ky=0), kx=1, ci=k&127
//   seg3 @131072 : py=1 G1,           K=128: ky=1, kx=1, ci=k&127
// frag addr within segment: a = ((k>>3)*128 + n)*8 + (k&7)
__global__ void k_prep(const float* __restrict__ w_def, const float* __restrict__ w_up,
                       float* __restrict__ w_def_t, unsigned short* __restrict__ WB)
{
    int idx = blockIdx.x * 256 + threadIdx.x;
    if (idx < 73728) {
        const int o  = idx & 127;
        const int c  = (idx >> 7) & 63;
        const int kk = idx >> 13;
        w_def_t[idx] = w_def[(o * CIN + c) * 9 + kk];
    }
    const int i2 = idx - 73728;
    if (i2 >= 0 && i2 < 147456) {
        const int j = i2 & 7;
        const int n = (i2 >> 3) & 127;
        int ky, kx, ci;
        if (i2 < 65536) {
            const int k = (i2 >> 10) * 8 + j;            // 0..511
            ky = (k >> 8) ? 0 : 2;
            kx = ((k >> 7) & 1) ? 0 : 2;
            ci = k & 127;
        } else if (i2 < 98304) {
            const int k = ((i2 - 65536) >> 10) * 8 + j;  // 0..255
            ky = 1;
            kx = (k >> 7) ? 0 : 2;
            ci = k & 127;
        } else if (i2 < 131072) {
            const int k = ((i2 - 98304) >> 10) * 8 + j;  // 0..255
            ky = (k >> 7) ? 0 : 2;
            kx = 1;
            ci = k & 127;
        } else {
            const int k = ((i2 - 131072) >> 10) * 8 + j; // 0..127
            ky = 1; kx = 1;
            ci = k & 127;
        }
        WB[i2] = f2bf(w_up[((ci * COUT + n) * 3 + ky) * 3 + kx]);
    }
}

// ---------------- offset conv (3x3, 64->18, pad 1) ----------------
__global__ __launch_bounds__(256) void k_offset_conv(
    const float* __restrict__ x, const float* __restrict__ w_off,
    const float* __restrict__ b_off, float* __restrict__ offs)
{
    const int idx = blockIdx.x * 256 + threadIdx.x;  // NB*NOFF*IH*IW
    const int w  = idx & 63;
    const int h  = (idx >> 6) & 63;
    const int oc = (idx >> 12) % NOFF;
    const int b  = idx / (NOFF * IH * IW);

    float acc = b_off[oc];
    const float* wp = w_off + oc * CIN * 9;
    const float* xb = x + b * (CIN * IH * IW);
    for (int ci = 0; ci < CIN; ++ci) {
        const float* plane = xb + ci * (IH * IW);
        const float* wc = wp + ci * 9;
        #pragma unroll
        for (int ki = 0; ki < 3; ++ki) {
            const int yy = h - PADC + ki;
            if (yy < 0 || yy >= IH) continue;
            const float* rowp = plane + yy * IW;
            #pragma unroll
            for (int kj = 0; kj < 3; ++kj) {
                const int xx = w - PADC + kj;
                if (xx < 0 || xx >= IW) continue;
                acc += rowp[xx] * wc[ki * 3 + kj];
            }
        }
    }
    offs[idx] = acc;
}

// ---------------- deformable conv ----------------
// block = (b, h0=2 rows). Writes feats channel-last bf16: feats_bf[b][h][w][o]
__global__ __launch_bounds__(256) void k_deform(
    const float* __restrict__ x, const float* __restrict__ offs,
    const float* __restrict__ w_def_t, const float* __restrict__ b_def,
    unsigned short* __restrict__ feats_bf)
{
    __shared__ float s_s[2][CIN][64];
    __shared__ float s_wk[CIN][COUT];
    __shared__ int   s_ci[2][4][64];
    __shared__ float s_cw[2][4][64];

    const int tid = threadIdx.x;
    const int b   = blockIdx.x >> 5;
    const int h0  = (blockIdx.x & 31) << 1;
    const int row = tid >> 7;
    const int ot  = (tid & 127) >> 3;
    const int wt  = tid & 7;
    const int o0  = ot * 8;
    const int w0  = wt * 8;

    const float* xb = x + b * (CIN * IH * IW);

    float acc[8][8] = {};

    for (int kk = 0; kk < 9; ++kk) {
        __syncthreads();
        {
            const float4* src = (const float4*)(w_def_t + kk * (CIN * COUT));
            float4* dst = (float4*)&s_wk[0][0];
            #pragma unroll
            for (int i = 0; i < 8; ++i) dst[tid + i * 256] = src[tid + i * 256];
        }
        if (tid < 128) {
            const int r = tid >> 6, w = tid & 63;
            const int h = h0 + r;
            const int ki = kk / 3, kj = kk - ki * 3;
            const float dy = offs[((b * NOFF + kk * 2) * IH + h) * IW + w];
            const float dx = offs[((b * NOFF + kk * 2 + 1) * IH + h) * IW + w];
            const float py = (float)(h - PADC + ki) + dy;
            const float px = (float)(w - PADC + kj) + dx;
            const float y0f = floorf(py), x0f = floorf(px);
            const float ly = py - y0f, lx = px - x0f;
            const int y0 = (int)y0f, x0 = (int)x0f;
            const float wy[2] = {1.f - ly, ly};
            const float wx[2] = {1.f - lx, lx};
            #pragma unroll
            for (int cy = 0; cy < 2; ++cy)
                #pragma unroll
                for (int cx = 0; cx < 2; ++cx) {
                    const int yy = y0 + cy, xx = x0 + cx;
                    const bool v = (yy >= 0) & (yy < IH) & (xx >= 0) & (xx < IW);
                    s_ci[r][cy * 2 + cx][w] = v ? (yy * IW + xx) : -1;
                    s_cw[r][cy * 2 + cx][w] = wy[cy] * wx[cx];
                }
        }
        __syncthreads();
        #pragma unroll 4
        for (int it = 0; it < 32; ++it) {
            const int i = tid + it * 256;
            const int w = i & 63, c = (i >> 6) & 63, r = i >> 12;
            const float* plane = xb + c * (IH * IW);
            float v = 0.f;
            #pragma unroll
            for (int cp = 0; cp < 4; ++cp) {
                const int   ii = s_ci[r][cp][w];
                const float cw = s_cw[r][cp][w];
                if (ii >= 0) v += plane[ii] * cw;
            }
            s_s[r][c][w] = v;
        }
        __syncthreads();
        for (int c = 0; c < CIN; ++c) {
            const float4* sp4 = (const float4*)&s_s[row][c][0];
            const float4 sa = sp4[wt * 2], sb = sp4[wt * 2 + 1];
            const float4* wp4 = (const float4*)&s_wk[c][0];
            const float4 wa = wp4[ot * 2], wb = wp4[ot * 2 + 1];
            const float sv[8] = {sa.x, sa.y, sa.z, sa.w, sb.x, sb.y, sb.z, sb.w};
            const float wv[8] = {wa.x, wa.y, wa.z, wa.w, wb.x, wb.y, wb.z, wb.w};
            #pragma unroll
            for (int j = 0; j < 8; ++j)
                #pragma unroll
                for (int p = 0; p < 8; ++p)
                    acc[j][p] += wv[j] * sv[p];
        }
    }
    const int h = h0 + row;
    float bd[8];
    #pragma unroll
    for (int j = 0; j < 8; ++j) bd[j] = b_def[o0 + j];
    #pragma unroll
    for (int p = 0; p < 8; ++p) {
        unsigned short* dst = feats_bf + ((size_t)((b * IH + h) * IW) + (w0 + p)) * COUT + o0;
        union { unsigned short u[8]; uint4 v; } pk;
        #pragma unroll
        for (int j = 0; j < 8; ++j) pk.u[j] = f2bf(acc[j][p] + bd[j]);
        *(uint4*)dst = pk.v;
    }
}

// ---------------- convT via MFMA, one block per (b, oy) ----------------
// feats row in LDS: [pad 128ci | 64px*128ci | pad 128ci] bf16 = 1056 granules of 16B,
// XOR-swizzled: phys = G ^ ((G>>4)&7). Two row slots (ky taps).
__global__ __launch_bounds__(256) void k_convT_mfma(
    const unsigned short* __restrict__ feats_bf, const unsigned short* __restrict__ WB,
    const float* __restrict__ b_up, float* __restrict__ y)
{
    __shared__ __align__(16) char smem[34048];   // 2*16896 rows / 4*8512 slabs (union)

    const int tid = threadIdx.x;
    const int l   = tid & 63;
    const int wv  = tid >> 6;
    const int ml  = l & 15;
    const int kg  = l >> 4;
    const int blk = blockIdx.x;
    const int oy  = blk % OYX;
    const int b   = blk / OYX;
    const int py  = oy & 1;
    const int ty  = oy >> 1;

    // ---- stage input rows ----
    const int nrow = py ? 1 : 2;
    int iys[2];
    if (py == 0) { iys[0] = ty - 1; iys[1] = (ty <= 63) ? ty : -1; }
    else         { iys[0] = ty;     iys[1] = -1; }

    for (int r = 0; r < nrow; ++r) {
        char* dstbase = smem + r * 16896;
        const int iy = iys[r];
        if (iy < 0 || iy > 63) {
            for (int i = tid; i < 1056; i += 256)
                *(uint4*)(dstbase + i * 16) = uint4{0, 0, 0, 0};   // full-set bijection: no swizzle needed
        } else {
            const unsigned short* src = feats_bf + (size_t)(b * IH + iy) * (IW * COUT);
            for (int i = tid; i < 1024; i += 256) {
                const uint4 v = *(const uint4*)(src + i * 8);
                const int G = 16 + i;
                const int phys = G ^ ((G >> 4) & 7);
                *(uint4*)(dstbase + phys * 16) = v;
            }
            if (tid < 32) {
                const int G = (tid < 16) ? tid : (1024 + tid);     // 0..15, 1040..1055
                const int phys = G ^ ((G >> 4) & 7);
                *(uint4*)(dstbase + phys * 16) = uint4{0, 0, 0, 0};
            }
        }
    }
    __syncthreads();

    const f32x4 fz = {0.f, 0.f, 0.f, 0.f};
    f32x4 acc0[5][2], acc1[4][2];
    #pragma unroll
    for (int m = 0; m < 5; ++m) { acc0[m][0] = fz; acc0[m][1] = fz; }
    #pragma unroll
    for (int m = 0; m < 4; ++m) { acc1[m][0] = fz; acc1[m][1] = fz; }

    const int n0   = wv * 32;
    const int nK0  = py ? 8 : 16;
    const int nK1  = py ? 4 : 8;
    const unsigned short* segG0 = WB + (py ? 65536 : 0);
    const unsigned short* segG1 = WB + (py ? 131072 : 98304);

    // ---- G0: even ox. K-run = 2 adjacent px (256 bf16), slots = ky taps ----
    for (int ks = 0; ks < nK0; ++ks) {
        const int kk   = ks * 32 + kg * 8;
        const int slot = kk >> 8;            // py=1: always 0
        const int kb   = (kk & 255) >> 3;
        const bf16x8 b0 = *(const bf16x8*)(segG0 + ((ks * 4 + kg) * 128 + n0 + ml) * 8);
        const bf16x8 b1 = *(const bf16x8*)(segG0 + ((ks * 4 + kg) * 128 + n0 + 16 + ml) * 8);
        #pragma unroll
        for (int mt = 0; mt < 5; ++mt) {
            int tx = mt * 16 + ml; if (tx > 64) tx = 64;       // clamp: rows >64 discarded
            const int G = tx * 16 + kb;                        // pad-aware: tx=0 hits leading pad
            const int phys = G ^ ((G >> 4) & 7);
            const bf16x8 a = *(const bf16x8*)(smem + slot * 16896 + phys * 16);
            acc0[mt][0] = __builtin_amdgcn_mfma_f32_16x16x32_bf16(a, b0, acc0[mt][0], 0, 0, 0);
            acc0[mt][1] = __builtin_amdgcn_mfma_f32_16x16x32_bf16(a, b1, acc0[mt][1], 0, 0, 0);
        }
    }
    // ---- G1: odd ox. K-run = 1 px (128 bf16) ----
    for (int ks = 0; ks < nK1; ++ks) {
        const int kk   = ks * 32 + kg * 8;
        const int slot = kk >> 7;            // py=1: always 0
        const int kb   = (kk & 127) >> 3;
        const bf16x8 b0 = *(const bf16x8*)(segG1 + ((ks * 4 + kg) * 128 + n0 + ml) * 8);
        const bf16x8 b1 = *(const bf16x8*)(segG1 + ((ks * 4 + kg) * 128 + n0 + 16 + ml) * 8);
        #pragma unroll
        for (int mt = 0; mt < 4; ++mt) {
            const int tx = mt * 16 + ml;
            const int G = 16 + tx * 16 + kb;                   // skip leading pad: ix = tx exactly
            const int phys = G ^ ((G >> 4) & 7);
            const bf16x8 a = *(const bf16x8*)(smem + slot * 16896 + phys * 16);
            acc1[mt][0] = __builtin_amdgcn_mfma_f32_16x16x32_bf16(a, b0, acc1[mt][0], 0, 0, 0);
            acc1[mt][1] = __builtin_amdgcn_mfma_f32_16x16x32_bf16(a, b1, acc1[mt][1], 0, 0, 0);
        }
    }

    // ---- epilogue: interleave even/odd ox via wave-private slab, coalesced store ----
    __syncthreads();
    float* slab = (float*)smem + wv * 2128;   // [16 co][133 ox]
    const int rrow = kg * 4;
    #pragma unroll
    for (int nt = 0; nt < 2; ++nt) {
        #pragma unroll
        for (int mt = 0; mt < 5; ++mt) {
            #pragma unroll
            for (int j = 0; j < 4; ++j) {
                const int tx = mt * 16 + rrow + j;
                if (tx <= 64) slab[ml * 133 + 2 * tx] = acc0[mt][nt][j];
            }
        }
        #pragma unroll
        for (int mt = 0; mt < 4; ++mt) {
            #pragma unroll
            for (int j = 0; j < 4; ++j) {
                const int tx = mt * 16 + rrow + j;
                slab[ml * 133 + 2 * tx + 1] = acc1[mt][nt][j];
            }
        }
        __syncthreads();
        #pragma unroll
        for (int r2 = 0; r2 < 16; ++r2) {
            const int co = n0 + nt * 16 + r2;
            const float bias = b_up[co];
            float* drow = y + ((size_t)(b * COUT + co) * OYX + oy) * OYX;
            drow[l]      = slab[r2 * 133 + l] + bias;
            drow[64 + l] = slab[r2 * 133 + 64 + l] + bias;
            if (l == 0) drow[128] = slab[r2 * 133 + 128] + bias;
        }
        __syncthreads();
    }
}

// ---------------- BN stats: one block per channel ----------------
__global__ __launch_bounds__(256) void k_bn_stats(const float* __restrict__ y, float* __restrict__ stats)
{
    const int c = blockIdx.x;
    const int tid = threadIdx.x;
    float s = 0.f, sq = 0.f;
    for (int i = tid; i < NB * SPO; i += 256) {
        const int b = i / SPO, sp = i - b * SPO;
        const float v = y[(size_t)(b * COUT + c) * SPO + sp];
        s += v; sq += v * v;
    }
    __shared__ float rs[256], rq[256];
    rs[tid] = s; rq[tid] = sq;
    __syncthreads();
    for (int off = 128; off > 0; off >>= 1) {
        if (tid < off) { rs[tid] += rs[tid + off]; rq[tid] += rq[tid + off]; }
        __syncthreads();
    }
    if (tid == 0) {
        const float n = (float)(NB * SPO);
        const float mean = rs[0] / n;
        const float var  = rq[0] / n - mean * mean;
        stats[c] = mean;
        stats[COUT + c] = rsqrtf(var + BNEPS);
    }
}

// ---------------- BN apply + ReLU (in place on d_out) ----------------
__global__ void k_bn_apply(float* __restrict__ y, const float* __restrict__ stats,
                           const float* __restrict__ gamma, const float* __restrict__ beta)
{
    const int i = blockIdx.x * 256 + threadIdx.x;
    const int c = (i / SPO) & (COUT - 1);
    const float mean = stats[c], rstd = stats[COUT + c];
    float v = y[i];
    v = (v - mean) * rstd * gamma[c] + beta[c];
    y[i] = fmaxf(v, 0.f);
}

extern "C" void kernel_launch(void* const* d_in, const int* in_sizes, int n_in,
                              void* d_out, int out_size, void* d_ws, size_t ws_size,
                              hipStream_t stream)
{
    const float* x     = (const float*)d_in[0];
    const float* w_off = (const float*)d_in[1];
    const float* b_off = (const float*)d_in[2];
    const float* w_def = (const float*)d_in[3];
    const float* b_def = (const float*)d_in[4];
    const float* w_up  = (const float*)d_in[5];
    const float* b_up  = (const float*)d_in[6];
    const float* gamma = (const float*)d_in[7];
    const float* beta  = (const float*)d_in[8];
    float* y = (float*)d_out;

    float* ws       = (float*)d_ws;
    float* offs     = ws;                     // 1,179,648 f32
    float* w_def_t  = offs + 1179648;         //    73,728 f32
    float* stats    = w_def_t + 73728;        //       256 f32
    unsigned short* feats_bf = (unsigned short*)(stats + 256);   // 8,388,608 bf16
    unsigned short* WB       = feats_bf + 8388608;               //   147,456 bf16

    k_prep       <<<dim3(864),    dim3(256), 0, stream>>>(w_def, w_up, w_def_t, WB);
    k_offset_conv<<<dim3(4608),   dim3(256), 0, stream>>>(x, w_off, b_off, offs);
    k_deform     <<<dim3(512),    dim3(256), 0, stream>>>(x, offs, w_def_t, b_def, feats_bf);
    k_convT_mfma <<<dim3(2064),   dim3(256), 0, stream>>>(feats_bf, WB, b_up, y);
    k_bn_stats   <<<dim3(128),    dim3(256), 0, stream>>>(y, stats);
    k_bn_apply   <<<dim3(133128), dim3(256), 0, stream>>>(y, stats, gamma, beta);
}

// Round 3
// 817.583 us; speedup vs baseline: 1.9925x; 1.3322x over previous
//
#include <hip/hip_runtime.h>
#include <math.h>

#define PADC 1
#define CIN  64
#define COUT 128
#define IH   64
#define IW   64
#define NB   16
#define OYX  129
#define NOFF 18
#define SPO  (OYX * OYX)   // 16641
#define BNEPS 1e-5f

typedef __attribute__((ext_vector_type(8))) short bf16x8;
typedef __attribute__((ext_vector_type(4))) float f32x4;

static __device__ __forceinline__ unsigned short f2bf(float f) {
    unsigned int b = __float_as_uint(f);
    unsigned int r = (b + 0x7FFFu + ((b >> 16) & 1u)) >> 16;   // RNE
    return (unsigned short)r;
}

// ---------------- weight prep ----------------
// WDF: deform weights in MFMA B-frag order:
//   WDF[((kk*8 + ks*4 + kg)*128 + n)*8 + j] = bf16(w_def[n][c=ks*32+kg*8+j][kk])
// WB: convT weights (4 segments, as in round 2)
__global__ void k_prep(const float* __restrict__ w_def, const float* __restrict__ w_up,
                       unsigned short* __restrict__ WDF, unsigned short* __restrict__ WB)
{
    int idx = blockIdx.x * 256 + threadIdx.x;
    if (idx < 73728) {
        const int j = idx & 7;
        const int n = (idx >> 3) & 127;
        const int g = idx >> 10;            // 0..71 = kk*8 + ks*4 + kg
        const int kg = g & 3, ks = (g >> 2) & 1, kk = g >> 3;
        const int c = ks * 32 + kg * 8 + j;
        WDF[idx] = f2bf(w_def[(n * CIN + c) * 9 + kk]);
    }
    const int i2 = idx - 73728;
    if (i2 >= 0 && i2 < 147456) {
        const int j = i2 & 7;
        const int n = (i2 >> 3) & 127;
        int ky, kx, ci;
        if (i2 < 65536) {
            const int k = (i2 >> 10) * 8 + j;            // 0..511
            ky = (k >> 8) ? 0 : 2;
            kx = ((k >> 7) & 1) ? 0 : 2;
            ci = k & 127;
        } else if (i2 < 98304) {
            const int k = ((i2 - 65536) >> 10) * 8 + j;  // 0..255
            ky = 1;
            kx = (k >> 7) ? 0 : 2;
            ci = k & 127;
        } else if (i2 < 131072) {
            const int k = ((i2 - 98304) >> 10) * 8 + j;  // 0..255
            ky = (k >> 7) ? 0 : 2;
            kx = 1;
            ci = k & 127;
        } else {
            const int k = ((i2 - 131072) >> 10) * 8 + j; // 0..127
            ky = 1; kx = 1;
            ci = k & 127;
        }
        WB[i2] = f2bf(w_up[((ci * COUT + n) * 3 + ky) * 3 + kx]);
    }
}

// ---------------- x transpose to channel-last bf16: xt[b][h][w][c] ----------------
__global__ __launch_bounds__(256) void k_xt(const float* __restrict__ x, unsigned short* __restrict__ xt)
{
    __shared__ unsigned short t[64][66];
    const int tid = threadIdx.x;
    const int h = blockIdx.x & 63, b = blockIdx.x >> 6;
    const int w = tid & 63, cq = tid >> 6;
    #pragma unroll
    for (int p = 0; p < 16; ++p) {
        const int c = p * 4 + cq;
        t[w][c] = f2bf(x[((size_t)((b * 64 + c) * 64) + h) * 64 + w]);
    }
    __syncthreads();
    const int w2 = tid >> 2, q = tid & 3;
    unsigned int pk[8];
    #pragma unroll
    for (int m = 0; m < 8; ++m)
        pk[m] = (unsigned int)t[w2][q * 16 + 2 * m] | ((unsigned int)t[w2][q * 16 + 2 * m + 1] << 16);
    uint4* dst = (uint4*)(xt + ((size_t)((b * 64 + h) * 64) + w2) * 64 + q * 16);
    dst[0] = uint4{pk[0], pk[1], pk[2], pk[3]};
    dst[1] = uint4{pk[4], pk[5], pk[6], pk[7]};
}

// ---------------- offset conv (3x3, 64->18, pad 1), f32 exact ----------------
__global__ __launch_bounds__(256) void k_offset_conv(
    const float* __restrict__ x, const float* __restrict__ w_off,
    const float* __restrict__ b_off, float* __restrict__ offs)
{
    const int idx = blockIdx.x * 256 + threadIdx.x;  // NB*NOFF*IH*IW
    const int w  = idx & 63;
    const int h  = (idx >> 6) & 63;
    const int oc = (idx >> 12) % NOFF;
    const int b  = idx / (NOFF * IH * IW);

    float acc = b_off[oc];
    const float* wp = w_off + oc * CIN * 9;
    const float* xb = x + b * (CIN * IH * IW);
    for (int ci = 0; ci < CIN; ++ci) {
        const float* plane = xb + ci * (IH * IW);
        const float* wc = wp + ci * 9;
        #pragma unroll
        for (int ki = 0; ki < 3; ++ki) {
            const int yy = h - PADC + ki;
            if (yy < 0 || yy >= IH) continue;
            const float* rowp = plane + yy * IW;
            #pragma unroll
            for (int kj = 0; kj < 3; ++kj) {
                const int xx = w - PADC + kj;
                if (xx < 0 || xx >= IW) continue;
                acc += rowp[xx] * wc[ki * 3 + kj];
            }
        }
    }
    offs[idx] = acc;
}

// ---------------- deformable conv via MFMA, 1 wave per (b, row) ----------------
// Corners gathered 8-channels-at-a-time from xt (global, L2-resident);
// A-fragments built in-register; B-fragments from WDF. feats_bf[b][h][w][o].
__global__ __launch_bounds__(64, 2) void k_deform_mfma(
    const unsigned short* __restrict__ xt, const float* __restrict__ offs,
    const unsigned short* __restrict__ WDF, const float* __restrict__ b_def,
    unsigned short* __restrict__ feats_bf)
{
    const int l  = threadIdx.x;
    const int ml = l & 15;
    const int kg = l >> 4;
    const int h  = blockIdx.x & 63;
    const int b  = blockIdx.x >> 6;

    const unsigned short* xb = xt + (size_t)b * (IH * IW * CIN);

    f32x4 acc[4][8];
    const f32x4 fz = {0.f, 0.f, 0.f, 0.f};
    #pragma unroll
    for (int mt = 0; mt < 4; ++mt)
        #pragma unroll
        for (int nt = 0; nt < 8; ++nt) acc[mt][nt] = fz;

    #pragma unroll 1
    for (int kk = 0; kk < 9; ++kk) {
        const int ki = kk / 3, kj = kk - 3 * ki;
        int   cidx[4][4];
        float cwgt[4][4];
        #pragma unroll
        for (int mt = 0; mt < 4; ++mt) {
            const int w = mt * 16 + ml;
            const float dy = offs[((b * NOFF + 2 * kk) * IH + h) * IW + w];
            const float dx = offs[((b * NOFF + 2 * kk + 1) * IH + h) * IW + w];
            const float py = (float)(h - PADC + ki) + dy;
            const float px = (float)(w - PADC + kj) + dx;
            const float y0f = floorf(py), x0f = floorf(px);
            const float ly = py - y0f, lx = px - x0f;
            const int y0 = (int)y0f, x0 = (int)x0f;
            const float wy[2] = {1.f - ly, ly};
            const float wx[2] = {1.f - lx, lx};
            #pragma unroll
            for (int cy = 0; cy < 2; ++cy)
                #pragma unroll
                for (int cx = 0; cx < 2; ++cx) {
                    const int yy = y0 + cy, xx = x0 + cx;
                    const bool v = (yy >= 0) & (yy < IH) & (xx >= 0) & (xx < IW);
                    cidx[mt][cy * 2 + cx] = v ? ((yy * IW + xx) * CIN) : -1;
                    cwgt[mt][cy * 2 + cx] = wy[cy] * wx[cx];
                }
        }
        #pragma unroll
        for (int ks = 0; ks < 2; ++ks) {
            bf16x8 bfr[8];
            #pragma unroll
            for (int nt = 0; nt < 8; ++nt)
                bfr[nt] = *(const bf16x8*)(WDF + ((size_t)((kk * 8 + ks * 4 + kg) * 128) + nt * 16 + ml) * 8);
            const int c0 = ks * 32 + kg * 8;
            #pragma unroll
            for (int mt = 0; mt < 4; ++mt) {
                float sf[8] = {0.f, 0.f, 0.f, 0.f, 0.f, 0.f, 0.f, 0.f};
                #pragma unroll
                for (int cp = 0; cp < 4; ++cp) {
                    const int ii = cidx[mt][cp];
                    const float wg = cwgt[mt][cp];
                    if (ii >= 0) {
                        const uint4 v = *(const uint4*)(xb + ii + c0);
                        const unsigned int u0 = v.x, u1 = v.y, u2 = v.z, u3 = v.w;
                        sf[0] += wg * __uint_as_float(u0 << 16);
                        sf[1] += wg * __uint_as_float(u0 & 0xFFFF0000u);
                        sf[2] += wg * __uint_as_float(u1 << 16);
                        sf[3] += wg * __uint_as_float(u1 & 0xFFFF0000u);
                        sf[4] += wg * __uint_as_float(u2 << 16);
                        sf[5] += wg * __uint_as_float(u2 & 0xFFFF0000u);
                        sf[6] += wg * __uint_as_float(u3 << 16);
                        sf[7] += wg * __uint_as_float(u3 & 0xFFFF0000u);
                    }
                }
                union { unsigned short us[8]; bf16x8 v; } pa;
                #pragma unroll
                for (int j = 0; j < 8; ++j) pa.us[j] = f2bf(sf[j]);
                #pragma unroll
                for (int nt = 0; nt < 8; ++nt)
                    acc[mt][nt] = __builtin_amdgcn_mfma_f32_16x16x32_bf16(pa.v, bfr[nt], acc[mt][nt], 0, 0, 0);
            }
        }
    }
    // epilogue: D row = mt*16 + kg*4 + j (pixel w), col = nt*16 + ml (channel o)
    #pragma unroll
    for (int nt = 0; nt < 8; ++nt) {
        const int o = nt * 16 + ml;
        const float bias = b_def[o];
        #pragma unroll
        for (int mt = 0; mt < 4; ++mt) {
            #pragma unroll
            for (int j = 0; j < 4; ++j) {
                const int w = mt * 16 + kg * 4 + j;
                feats_bf[((size_t)((b * IH + h) * IW) + w) * COUT + o] = f2bf(acc[mt][nt][j] + bias);
            }
        }
    }
}

// ---------------- convT via MFMA, one block per (b, oy) ----------------
__global__ __launch_bounds__(256) void k_convT_mfma(
    const unsigned short* __restrict__ feats_bf, const unsigned short* __restrict__ WB,
    const float* __restrict__ b_up, float* __restrict__ y)
{
    __shared__ __align__(16) char smem[34048];   // 2*16896 rows / 4*8512 slabs (union)

    const int tid = threadIdx.x;
    const int l   = tid & 63;
    const int wv  = tid >> 6;
    const int ml  = l & 15;
    const int kg  = l >> 4;
    const int blk = blockIdx.x;
    const int oy  = blk % OYX;
    const int b   = blk / OYX;
    const int py  = oy & 1;
    const int ty  = oy >> 1;

    const int nrow = py ? 1 : 2;
    int iys[2];
    if (py == 0) { iys[0] = ty - 1; iys[1] = (ty <= 63) ? ty : -1; }
    else         { iys[0] = ty;     iys[1] = -1; }

    for (int r = 0; r < nrow; ++r) {
        char* dstbase = smem + r * 16896;
        const int iy = iys[r];
        if (iy < 0 || iy > 63) {
            for (int i = tid; i < 1056; i += 256)
                *(uint4*)(dstbase + i * 16) = uint4{0, 0, 0, 0};
        } else {
            const unsigned short* src = feats_bf + (size_t)(b * IH + iy) * (IW * COUT);
            for (int i = tid; i < 1024; i += 256) {
                const uint4 v = *(const uint4*)(src + i * 8);
                const int G = 16 + i;
                const int phys = G ^ ((G >> 4) & 7);
                *(uint4*)(dstbase + phys * 16) = v;
            }
            if (tid < 32) {
                const int G = (tid < 16) ? tid : (1024 + tid);
                const int phys = G ^ ((G >> 4) & 7);
                *(uint4*)(dstbase + phys * 16) = uint4{0, 0, 0, 0};
            }
        }
    }
    __syncthreads();

    const f32x4 fz = {0.f, 0.f, 0.f, 0.f};
    f32x4 acc0[5][2], acc1[4][2];
    #pragma unroll
    for (int m = 0; m < 5; ++m) { acc0[m][0] = fz; acc0[m][1] = fz; }
    #pragma unroll
    for (int m = 0; m < 4; ++m) { acc1[m][0] = fz; acc1[m][1] = fz; }

    const int n0   = wv * 32;
    const int nK0  = py ? 8 : 16;
    const int nK1  = py ? 4 : 8;
    const unsigned short* segG0 = WB + (py ? 65536 : 0);
    const unsigned short* segG1 = WB + (py ? 131072 : 98304);

    for (int ks = 0; ks < nK0; ++ks) {
        const int kk   = ks * 32 + kg * 8;
        const int slot = kk >> 8;
        const int kb   = (kk & 255) >> 3;
        const bf16x8 b0 = *(const bf16x8*)(segG0 + ((ks * 4 + kg) * 128 + n0 + ml) * 8);
        const bf16x8 b1 = *(const bf16x8*)(segG0 + ((ks * 4 + kg) * 128 + n0 + 16 + ml) * 8);
        #pragma unroll
        for (int mt = 0; mt < 5; ++mt) {
            int tx = mt * 16 + ml; if (tx > 64) tx = 64;
            const int G = tx * 16 + kb;
            const int phys = G ^ ((G >> 4) & 7);
            const bf16x8 a = *(const bf16x8*)(smem + slot * 16896 + phys * 16);
            acc0[mt][0] = __builtin_amdgcn_mfma_f32_16x16x32_bf16(a, b0, acc0[mt][0], 0, 0, 0);
            acc0[mt][1] = __builtin_amdgcn_mfma_f32_16x16x32_bf16(a, b1, acc0[mt][1], 0, 0, 0);
        }
    }
    for (int ks = 0; ks < nK1; ++ks) {
        const int kk   = ks * 32 + kg * 8;
        const int slot = kk >> 7;
        const int kb   = (kk & 127) >> 3;
        const bf16x8 b0 = *(const bf16x8*)(segG1 + ((ks * 4 + kg) * 128 + n0 + ml) * 8);
        const bf16x8 b1 = *(const bf16x8*)(segG1 + ((ks * 4 + kg) * 128 + n0 + 16 + ml) * 8);
        #pragma unroll
        for (int mt = 0; mt < 4; ++mt) {
            const int tx = mt * 16 + ml;
            const int G = 16 + tx * 16 + kb;
            const int phys = G ^ ((G >> 4) & 7);
            const bf16x8 a = *(const bf16x8*)(smem + slot * 16896 + phys * 16);
            acc1[mt][0] = __builtin_amdgcn_mfma_f32_16x16x32_bf16(a, b0, acc1[mt][0], 0, 0, 0);
            acc1[mt][1] = __builtin_amdgcn_mfma_f32_16x16x32_bf16(a, b1, acc1[mt][1], 0, 0, 0);
        }
    }

    __syncthreads();
    float* slab = (float*)smem + wv * 2128;   // [16 co][133 ox]
    const int rrow = kg * 4;
    #pragma unroll
    for (int nt = 0; nt < 2; ++nt) {
        #pragma unroll
        for (int mt = 0; mt < 5; ++mt) {
            #pragma unroll
            for (int j = 0; j < 4; ++j) {
                const int tx = mt * 16 + rrow + j;
                if (tx <= 64) slab[ml * 133 + 2 * tx] = acc0[mt][nt][j];
            }
        }
        #pragma unroll
        for (int mt = 0; mt < 4; ++mt) {
            #pragma unroll
            for (int j = 0; j < 4; ++j) {
                const int tx = mt * 16 + rrow + j;
                slab[ml * 133 + 2 * tx + 1] = acc1[mt][nt][j];
            }
        }
        __syncthreads();
        #pragma unroll
        for (int r2 = 0; r2 < 16; ++r2) {
            const int co = n0 + nt * 16 + r2;
            const float bias = b_up[co];
            float* drow = y + ((size_t)(b * COUT + co) * OYX + oy) * OYX;
            drow[l]      = slab[r2 * 133 + l] + bias;
            drow[64 + l] = slab[r2 * 133 + 64 + l] + bias;
            if (l == 0) drow[128] = slab[r2 * 133 + 128] + bias;
        }
        __syncthreads();
    }
}

// ---------------- BN stats: one block per channel ----------------
__global__ __launch_bounds__(256) void k_bn_stats(const float* __restrict__ y, float* __restrict__ stats)
{
    const int c = blockIdx.x;
    const int tid = threadIdx.x;
    float s = 0.f, sq = 0.f;
    for (int i = tid; i < NB * SPO; i += 256) {
        const int b = i / SPO, sp = i - b * SPO;
        const float v = y[(size_t)(b * COUT + c) * SPO + sp];
        s += v; sq += v * v;
    }
    __shared__ float rs[256], rq[256];
    rs[tid] = s; rq[tid] = sq;
    __syncthreads();
    for (int off = 128; off > 0; off >>= 1) {
        if (tid < off) { rs[tid] += rs[tid + off]; rq[tid] += rq[tid + off]; }
        __syncthreads();
    }
    if (tid == 0) {
        const float n = (float)(NB * SPO);
        const float mean = rs[0] / n;
        const float var  = rq[0] / n - mean * mean;
        stats[c] = mean;
        stats[COUT + c] = rsqrtf(var + BNEPS);
    }
}

// ---------------- BN apply + ReLU (in place on d_out) ----------------
__global__ void k_bn_apply(float* __restrict__ y, const float* __restrict__ stats,
                           const float* __restrict__ gamma, const float* __restrict__ beta)
{
    const int i = blockIdx.x * 256 + threadIdx.x;
    const int c = (i / SPO) & (COUT - 1);
    const float mean = stats[c], rstd = stats[COUT + c];
    float v = y[i];
    v = (v - mean) * rstd * gamma[c] + beta[c];
    y[i] = fmaxf(v, 0.f);
}

extern "C" void kernel_launch(void* const* d_in, const int* in_sizes, int n_in,
                              void* d_out, int out_size, void* d_ws, size_t ws_size,
                              hipStream_t stream)
{
    const float* x     = (const float*)d_in[0];
    const float* w_off = (const float*)d_in[1];
    const float* b_off = (const float*)d_in[2];
    const float* w_def = (const float*)d_in[3];
    const float* b_def = (const float*)d_in[4];
    const float* w_up  = (const float*)d_in[5];
    const float* b_up  = (const float*)d_in[6];
    const float* gamma = (const float*)d_in[7];
    const float* beta  = (const float*)d_in[8];
    float* y = (float*)d_out;

    float* ws    = (float*)d_ws;
    float* offs  = ws;                    // 1,179,648 f32
    float* stats = offs + 1179648;        //       256 f32
    unsigned short* xt       = (unsigned short*)(stats + 256);   // 4,194,304 bf16
    unsigned short* WDF      = xt + 4194304;                     //    73,728 bf16
    unsigned short* feats_bf = WDF + 73728;                      // 8,388,608 bf16
    unsigned short* WB       = feats_bf + 8388608;               //   147,456 bf16

    k_prep        <<<dim3(864),    dim3(256), 0, stream>>>(w_def, w_up, WDF, WB);
    k_xt          <<<dim3(1024),   dim3(256), 0, stream>>>(x, xt);
    k_offset_conv <<<dim3(4608),   dim3(256), 0, stream>>>(x, w_off, b_off, offs);
    k_deform_mfma <<<dim3(1024),   dim3(64),  0, stream>>>(xt, offs, WDF, b_def, feats_bf);
    k_convT_mfma  <<<dim3(2064),   dim3(256), 0, stream>>>(feats_bf, WB, b_up, y);
    k_bn_stats    <<<dim3(128),    dim3(256), 0, stream>>>(y, stats);
    k_bn_apply    <<<dim3(133128), dim3(256), 0, stream>>>(y, stats, gamma, beta);
}

// Round 4
// 557.058 us; speedup vs baseline: 2.9243x; 1.4677x over previous
//
#include <hip/hip_runtime.h>
#include <math.h>

#define PADC 1
#define CIN  64
#define COUT 128
#define IH   64
#define IW   64
#define NB   16
#define OYX  129
#define NOFF 18
#define SPO  (OYX * OYX)   // 16641
#define BNEPS 1e-5f
#define NBLK_CT (NB * OYX) // 2064 convT blocks

typedef __attribute__((ext_vector_type(8))) short bf16x8;
typedef __attribute__((ext_vector_type(4))) float f32x4;

static __device__ __forceinline__ unsigned short f2bf(float f) {
    unsigned int b = __float_as_uint(f);
    unsigned int r = (b + 0x7FFFu + ((b >> 16) & 1u)) >> 16;   // RNE
    return (unsigned short)r;
}

// ---------------- weight prep ----------------
__global__ void k_prep(const float* __restrict__ w_def, const float* __restrict__ w_up,
                       unsigned short* __restrict__ WDF, unsigned short* __restrict__ WB)
{
    int idx = blockIdx.x * 256 + threadIdx.x;
    if (idx < 73728) {
        const int j = idx & 7;
        const int n = (idx >> 3) & 127;
        const int g = idx >> 10;            // 0..71 = kk*8 + ks*4 + kg
        const int kg = g & 3, ks = (g >> 2) & 1, kk = g >> 3;
        const int c = ks * 32 + kg * 8 + j;
        WDF[idx] = f2bf(w_def[(n * CIN + c) * 9 + kk]);
    }
    const int i2 = idx - 73728;
    if (i2 >= 0 && i2 < 147456) {
        const int j = i2 & 7;
        const int n = (i2 >> 3) & 127;
        int ky, kx, ci;
        if (i2 < 65536) {
            const int k = (i2 >> 10) * 8 + j;            // 0..511
            ky = (k >> 8) ? 0 : 2;
            kx = ((k >> 7) & 1) ? 0 : 2;
            ci = k & 127;
        } else if (i2 < 98304) {
            const int k = ((i2 - 65536) >> 10) * 8 + j;  // 0..255
            ky = 1;
            kx = (k >> 7) ? 0 : 2;
            ci = k & 127;
        } else if (i2 < 131072) {
            const int k = ((i2 - 98304) >> 10) * 8 + j;  // 0..255
            ky = (k >> 7) ? 0 : 2;
            kx = 1;
            ci = k & 127;
        } else {
            const int k = ((i2 - 131072) >> 10) * 8 + j; // 0..127
            ky = 1; kx = 1;
            ci = k & 127;
        }
        WB[i2] = f2bf(w_up[((ci * COUT + n) * 3 + ky) * 3 + kx]);
    }
}

// ---------------- x transpose to channel-last bf16: xt[b][h][w][c] ----------------
__global__ __launch_bounds__(256) void k_xt(const float* __restrict__ x, unsigned short* __restrict__ xt)
{
    __shared__ unsigned short t[64][66];
    const int tid = threadIdx.x;
    const int h = blockIdx.x & 63, b = blockIdx.x >> 6;
    const int w = tid & 63, cq = tid >> 6;
    #pragma unroll
    for (int p = 0; p < 16; ++p) {
        const int c = p * 4 + cq;
        t[w][c] = f2bf(x[((size_t)((b * 64 + c) * 64) + h) * 64 + w]);
    }
    __syncthreads();
    const int w2 = tid >> 2, q = tid & 3;
    unsigned int pk[8];
    #pragma unroll
    for (int m = 0; m < 8; ++m)
        pk[m] = (unsigned int)t[w2][q * 16 + 2 * m] | ((unsigned int)t[w2][q * 16 + 2 * m + 1] << 16);
    uint4* dst = (uint4*)(xt + ((size_t)((b * 64 + h) * 64) + w2) * 64 + q * 16);
    dst[0] = uint4{pk[0], pk[1], pk[2], pk[3]};
    dst[1] = uint4{pk[4], pk[5], pk[6], pk[7]};
}

// ---------------- offset conv (3x3, 64->18, pad 1), f32 exact ----------------
__global__ __launch_bounds__(256) void k_offset_conv(
    const float* __restrict__ x, const float* __restrict__ w_off,
    const float* __restrict__ b_off, float* __restrict__ offs)
{
    const int idx = blockIdx.x * 256 + threadIdx.x;  // NB*NOFF*IH*IW
    const int w  = idx & 63;
    const int h  = (idx >> 6) & 63;
    const int oc = (idx >> 12) % NOFF;
    const int b  = idx / (NOFF * IH * IW);

    float acc = b_off[oc];
    const float* wp = w_off + oc * CIN * 9;
    const float* xb = x + b * (CIN * IH * IW);
    for (int ci = 0; ci < CIN; ++ci) {
        const float* plane = xb + ci * (IH * IW);
        const float* wc = wp + ci * 9;
        #pragma unroll
        for (int ki = 0; ki < 3; ++ki) {
            const int yy = h - PADC + ki;
            if (yy < 0 || yy >= IH) continue;
            const float* rowp = plane + yy * IW;
            #pragma unroll
            for (int kj = 0; kj < 3; ++kj) {
                const int xx = w - PADC + kj;
                if (xx < 0 || xx >= IW) continue;
                acc += rowp[xx] * wc[ki * 3 + kj];
            }
        }
    }
    offs[idx] = acc;
}

// ---------------- deformable conv via MFMA, 1 wave per (b, row) ----------------
__global__ __launch_bounds__(64, 2) void k_deform_mfma(
    const unsigned short* __restrict__ xt, const float* __restrict__ offs,
    const unsigned short* __restrict__ WDF, const float* __restrict__ b_def,
    unsigned short* __restrict__ feats_bf)
{
    const int l  = threadIdx.x;
    const int ml = l & 15;
    const int kg = l >> 4;
    const int h  = blockIdx.x & 63;
    const int b  = blockIdx.x >> 6;

    const unsigned short* xb = xt + (size_t)b * (IH * IW * CIN);

    f32x4 acc[4][8];
    const f32x4 fz = {0.f, 0.f, 0.f, 0.f};
    #pragma unroll
    for (int mt = 0; mt < 4; ++mt)
        #pragma unroll
        for (int nt = 0; nt < 8; ++nt) acc[mt][nt] = fz;

    #pragma unroll 1
    for (int kk = 0; kk < 9; ++kk) {
        const int ki = kk / 3, kj = kk - 3 * ki;
        int   cidx[4][4];
        float cwgt[4][4];
        #pragma unroll
        for (int mt = 0; mt < 4; ++mt) {
            const int w = mt * 16 + ml;
            const float dy = offs[((b * NOFF + 2 * kk) * IH + h) * IW + w];
            const float dx = offs[((b * NOFF + 2 * kk + 1) * IH + h) * IW + w];
            const float py = (float)(h - PADC + ki) + dy;
            const float px = (float)(w - PADC + kj) + dx;
            const float y0f = floorf(py), x0f = floorf(px);
            const float ly = py - y0f, lx = px - x0f;
            const int y0 = (int)y0f, x0 = (int)x0f;
            const float wy[2] = {1.f - ly, ly};
            const float wx[2] = {1.f - lx, lx};
            #pragma unroll
            for (int cy = 0; cy < 2; ++cy)
                #pragma unroll
                for (int cx = 0; cx < 2; ++cx) {
                    const int yy = y0 + cy, xx = x0 + cx;
                    const bool v = (yy >= 0) & (yy < IH) & (xx >= 0) & (xx < IW);
                    cidx[mt][cy * 2 + cx] = v ? ((yy * IW + xx) * CIN) : -1;
                    cwgt[mt][cy * 2 + cx] = wy[cy] * wx[cx];
                }
        }
        #pragma unroll
        for (int ks = 0; ks < 2; ++ks) {
            bf16x8 bfr[8];
            #pragma unroll
            for (int nt = 0; nt < 8; ++nt)
                bfr[nt] = *(const bf16x8*)(WDF + ((size_t)((kk * 8 + ks * 4 + kg) * 128) + nt * 16 + ml) * 8);
            const int c0 = ks * 32 + kg * 8;
            #pragma unroll
            for (int mt = 0; mt < 4; ++mt) {
                float sf[8] = {0.f, 0.f, 0.f, 0.f, 0.f, 0.f, 0.f, 0.f};
                #pragma unroll
                for (int cp = 0; cp < 4; ++cp) {
                    const int ii = cidx[mt][cp];
                    const float wg = cwgt[mt][cp];
                    if (ii >= 0) {
                        const uint4 v = *(const uint4*)(xb + ii + c0);
                        const unsigned int u0 = v.x, u1 = v.y, u2 = v.z, u3 = v.w;
                        sf[0] += wg * __uint_as_float(u0 << 16);
                        sf[1] += wg * __uint_as_float(u0 & 0xFFFF0000u);
                        sf[2] += wg * __uint_as_float(u1 << 16);
                        sf[3] += wg * __uint_as_float(u1 & 0xFFFF0000u);
                        sf[4] += wg * __uint_as_float(u2 << 16);
                        sf[5] += wg * __uint_as_float(u2 & 0xFFFF0000u);
                        sf[6] += wg * __uint_as_float(u3 << 16);
                        sf[7] += wg * __uint_as_float(u3 & 0xFFFF0000u);
                    }
                }
                union { unsigned short us[8]; bf16x8 v; } pa;
                #pragma unroll
                for (int j = 0; j < 8; ++j) pa.us[j] = f2bf(sf[j]);
                #pragma unroll
                for (int nt = 0; nt < 8; ++nt)
                    acc[mt][nt] = __builtin_amdgcn_mfma_f32_16x16x32_bf16(pa.v, bfr[nt], acc[mt][nt], 0, 0, 0);
            }
        }
    }
    #pragma unroll
    for (int nt = 0; nt < 8; ++nt) {
        const int o = nt * 16 + ml;
        const float bias = b_def[o];
        #pragma unroll
        for (int mt = 0; mt < 4; ++mt) {
            #pragma unroll
            for (int j = 0; j < 4; ++j) {
                const int w = mt * 16 + kg * 4 + j;
                feats_bf[((size_t)((b * IH + h) * IW) + w) * COUT + o] = f2bf(acc[mt][nt][j] + bias);
            }
        }
    }
}

// ---------------- convT via MFMA + fused BN partial stats ----------------
__global__ __launch_bounds__(256) void k_convT_mfma(
    const unsigned short* __restrict__ feats_bf, const unsigned short* __restrict__ WB,
    const float* __restrict__ b_up, float* __restrict__ y, float* __restrict__ partials)
{
    __shared__ __align__(16) char smem[34048];   // 2*16896 rows / 4*8512 slabs (union)

    const int tid = threadIdx.x;
    const int l   = tid & 63;
    const int wv  = tid >> 6;
    const int ml  = l & 15;
    const int kg  = l >> 4;
    const int blk = blockIdx.x;
    const int oy  = blk % OYX;
    const int b   = blk / OYX;
    const int py  = oy & 1;
    const int ty  = oy >> 1;

    const int nrow = py ? 1 : 2;
    int iys[2];
    if (py == 0) { iys[0] = ty - 1; iys[1] = (ty <= 63) ? ty : -1; }
    else         { iys[0] = ty;     iys[1] = -1; }

    for (int r = 0; r < nrow; ++r) {
        char* dstbase = smem + r * 16896;
        const int iy = iys[r];
        if (iy < 0 || iy > 63) {
            for (int i = tid; i < 1056; i += 256)
                *(uint4*)(dstbase + i * 16) = uint4{0, 0, 0, 0};
        } else {
            const unsigned short* src = feats_bf + (size_t)(b * IH + iy) * (IW * COUT);
            for (int i = tid; i < 1024; i += 256) {
                const uint4 v = *(const uint4*)(src + i * 8);
                const int G = 16 + i;
                const int phys = G ^ ((G >> 4) & 7);
                *(uint4*)(dstbase + phys * 16) = v;
            }
            if (tid < 32) {
                const int G = (tid < 16) ? tid : (1024 + tid);
                const int phys = G ^ ((G >> 4) & 7);
                *(uint4*)(dstbase + phys * 16) = uint4{0, 0, 0, 0};
            }
        }
    }
    __syncthreads();

    const f32x4 fz = {0.f, 0.f, 0.f, 0.f};
    f32x4 acc0[5][2], acc1[4][2];
    #pragma unroll
    for (int m = 0; m < 5; ++m) { acc0[m][0] = fz; acc0[m][1] = fz; }
    #pragma unroll
    for (int m = 0; m < 4; ++m) { acc1[m][0] = fz; acc1[m][1] = fz; }

    const int n0   = wv * 32;
    const int nK0  = py ? 8 : 16;
    const int nK1  = py ? 4 : 8;
    const unsigned short* segG0 = WB + (py ? 65536 : 0);
    const unsigned short* segG1 = WB + (py ? 131072 : 98304);

    for (int ks = 0; ks < nK0; ++ks) {
        const int kk   = ks * 32 + kg * 8;
        const int slot = kk >> 8;
        const int kb   = (kk & 255) >> 3;
        const bf16x8 b0 = *(const bf16x8*)(segG0 + ((ks * 4 + kg) * 128 + n0 + ml) * 8);
        const bf16x8 b1 = *(const bf16x8*)(segG0 + ((ks * 4 + kg) * 128 + n0 + 16 + ml) * 8);
        #pragma unroll
        for (int mt = 0; mt < 5; ++mt) {
            int tx = mt * 16 + ml; if (tx > 64) tx = 64;
            const int G = tx * 16 + kb;
            const int phys = G ^ ((G >> 4) & 7);
            const bf16x8 a = *(const bf16x8*)(smem + slot * 16896 + phys * 16);
            acc0[mt][0] = __builtin_amdgcn_mfma_f32_16x16x32_bf16(a, b0, acc0[mt][0], 0, 0, 0);
            acc0[mt][1] = __builtin_amdgcn_mfma_f32_16x16x32_bf16(a, b1, acc0[mt][1], 0, 0, 0);
        }
    }
    for (int ks = 0; ks < nK1; ++ks) {
        const int kk   = ks * 32 + kg * 8;
        const int slot = kk >> 7;
        const int kb   = (kk & 127) >> 3;
        const bf16x8 b0 = *(const bf16x8*)(segG1 + ((ks * 4 + kg) * 128 + n0 + ml) * 8);
        const bf16x8 b1 = *(const bf16x8*)(segG1 + ((ks * 4 + kg) * 128 + n0 + 16 + ml) * 8);
        #pragma unroll
        for (int mt = 0; mt < 4; ++mt) {
            const int tx = mt * 16 + ml;
            const int G = 16 + tx * 16 + kb;
            const int phys = G ^ ((G >> 4) & 7);
            const bf16x8 a = *(const bf16x8*)(smem + slot * 16896 + phys * 16);
            acc1[mt][0] = __builtin_amdgcn_mfma_f32_16x16x32_bf16(a, b0, acc1[mt][0], 0, 0, 0);
            acc1[mt][1] = __builtin_amdgcn_mfma_f32_16x16x32_bf16(a, b1, acc1[mt][1], 0, 0, 0);
        }
    }

    __syncthreads();
    float* slab = (float*)smem + wv * 2128;   // [16 co][133 ox]
    const int rrow = kg * 4;
    #pragma unroll
    for (int nt = 0; nt < 2; ++nt) {
        #pragma unroll
        for (int mt = 0; mt < 5; ++mt) {
            #pragma unroll
            for (int j = 0; j < 4; ++j) {
                const int tx = mt * 16 + rrow + j;
                if (tx <= 64) slab[ml * 133 + 2 * tx] = acc0[mt][nt][j];
            }
        }
        #pragma unroll
        for (int mt = 0; mt < 4; ++mt) {
            #pragma unroll
            for (int j = 0; j < 4; ++j) {
                const int tx = mt * 16 + rrow + j;
                slab[ml * 133 + 2 * tx + 1] = acc1[mt][nt][j];
            }
        }
        __syncthreads();
        #pragma unroll
        for (int r2 = 0; r2 < 16; ++r2) {
            const int co = n0 + nt * 16 + r2;
            const float bias = b_up[co];
            float* drow = y + ((size_t)(b * COUT + co) * OYX + oy) * OYX;
            const float v0 = slab[r2 * 133 + l] + bias;
            const float v1 = slab[r2 * 133 + 64 + l] + bias;
            drow[l]      = v0;
            drow[64 + l] = v1;
            float v2 = 0.f;
            if (l == 0) { v2 = slab[r2 * 133 + 128] + bias; drow[128] = v2; }
            // fused BN partial stats: row sum / sumsq over 129 ox
            float s = v0 + v1 + v2;
            float q = v0 * v0 + v1 * v1 + v2 * v2;
            #pragma unroll
            for (int off = 32; off; off >>= 1) {
                s += __shfl_xor(s, off, 64);
                q += __shfl_xor(q, off, 64);
            }
            if (l == 0) {
                float* pp = partials + ((size_t)blk * COUT + co) * 2;
                pp[0] = s; pp[1] = q;
            }
        }
        __syncthreads();
    }
}

// ---------------- BN finalize: reduce per-block partials ----------------
__global__ __launch_bounds__(256) void k_bn_final(const float* __restrict__ partials,
                                                  float* __restrict__ stats)
{
    const int c = blockIdx.x;      // 128
    const int tid = threadIdx.x;
    float s = 0.f, q = 0.f;
    for (int i = tid; i < NBLK_CT; i += 256) {
        const float* pp = partials + ((size_t)i * COUT + c) * 2;
        s += pp[0]; q += pp[1];
    }
    __shared__ float rs[256], rq[256];
    rs[tid] = s; rq[tid] = q;
    __syncthreads();
    for (int off = 128; off > 0; off >>= 1) {
        if (tid < off) { rs[tid] += rs[tid + off]; rq[tid] += rq[tid + off]; }
        __syncthreads();
    }
    if (tid == 0) {
        const float n = (float)(NB * SPO);
        const float mean = rs[0] / n;
        const float var  = rq[0] / n - mean * mean;
        stats[c] = mean;
        stats[COUT + c] = rsqrtf(var + BNEPS);
    }
}

// ---------------- BN apply + ReLU (in place on d_out) ----------------
__global__ void k_bn_apply(float* __restrict__ y, const float* __restrict__ stats,
                           const float* __restrict__ gamma, const float* __restrict__ beta)
{
    const int i = blockIdx.x * 256 + threadIdx.x;
    const int c = (i / SPO) & (COUT - 1);
    const float mean = stats[c], rstd = stats[COUT + c];
    float v = y[i];
    v = (v - mean) * rstd * gamma[c] + beta[c];
    y[i] = fmaxf(v, 0.f);
}

extern "C" void kernel_launch(void* const* d_in, const int* in_sizes, int n_in,
                              void* d_out, int out_size, void* d_ws, size_t ws_size,
                              hipStream_t stream)
{
    const float* x     = (const float*)d_in[0];
    const float* w_off = (const float*)d_in[1];
    const float* b_off = (const float*)d_in[2];
    const float* w_def = (const float*)d_in[3];
    const float* b_def = (const float*)d_in[4];
    const float* w_up  = (const float*)d_in[5];
    const float* b_up  = (const float*)d_in[6];
    const float* gamma = (const float*)d_in[7];
    const float* beta  = (const float*)d_in[8];
    float* y = (float*)d_out;

    float* ws       = (float*)d_ws;
    float* offs     = ws;                     // 1,179,648 f32
    float* stats    = offs + 1179648;         //       256 f32
    float* partials = stats + 256;            //   528,384 f32
    unsigned short* xt       = (unsigned short*)(partials + 528384);  // 4,194,304 bf16
    unsigned short* WDF      = xt + 4194304;                          //    73,728 bf16
    unsigned short* feats_bf = WDF + 73728;                           // 8,388,608 bf16
    unsigned short* WB       = feats_bf + 8388608;                    //   147,456 bf16

    k_prep        <<<dim3(864),    dim3(256), 0, stream>>>(w_def, w_up, WDF, WB);
    k_xt          <<<dim3(1024),   dim3(256), 0, stream>>>(x, xt);
    k_offset_conv <<<dim3(4608),   dim3(256), 0, stream>>>(x, w_off, b_off, offs);
    k_deform_mfma <<<dim3(1024),   dim3(64),  0, stream>>>(xt, offs, WDF, b_def, feats_bf);
    k_convT_mfma  <<<dim3(NBLK_CT),dim3(256), 0, stream>>>(feats_bf, WB, b_up, y, partials);
    k_bn_final    <<<dim3(128),    dim3(256), 0, stream>>>(partials, stats);
    k_bn_apply    <<<dim3(133128), dim3(256), 0, stream>>>(y, stats, gamma, beta);
}

// Round 5
// 274.813 us; speedup vs baseline: 5.9278x; 2.0270x over previous
//
#include <hip/hip_runtime.h>
#include <math.h>

#define PADC 1
#define CIN  64
#define COUT 128
#define IH   64
#define IW   64
#define NB   16
#define OYX  129
#define NOFF 18
#define SPO  (OYX * OYX)   // 16641
#define BNEPS 1e-5f
#define NBLK_CT (NB * OYX) // 2064 convT blocks

typedef __attribute__((ext_vector_type(8))) short bf16x8;
typedef __attribute__((ext_vector_type(4))) float f32x4;

static __device__ __forceinline__ unsigned short f2bf(float f) {
    unsigned int b = __float_as_uint(f);
    unsigned int r = (b + 0x7FFFu + ((b >> 16) & 1u)) >> 16;   // RNE
    return (unsigned short)r;
}

// ---------------- weight prep ----------------
// WDF: deform weights B-frag order (73728)
// WB : convT weights, 4 segments (147456)
// WOF: offset-conv weights B-frag order, N padded 18->32 (18432):
//   WOF[((s*4+kg)*32 + n)*8 + j] = bf16(w_off[n][c][ki][kj]),
//   k = s*32+kg*8+j, kk = k>>6, c = k&63, ki=kk/3, kj=kk%3; n>=18 -> 0
__global__ void k_prep(const float* __restrict__ w_def, const float* __restrict__ w_up,
                       const float* __restrict__ w_off,
                       unsigned short* __restrict__ WDF, unsigned short* __restrict__ WB,
                       unsigned short* __restrict__ WOF)
{
    int idx = blockIdx.x * 256 + threadIdx.x;
    if (idx < 73728) {
        const int j = idx & 7;
        const int n = (idx >> 3) & 127;
        const int g = idx >> 10;            // 0..71 = kk*8 + ks*4 + kg
        const int kg = g & 3, ks = (g >> 2) & 1, kk = g >> 3;
        const int c = ks * 32 + kg * 8 + j;
        WDF[idx] = f2bf(w_def[(n * CIN + c) * 9 + kk]);
    }
    const int i2 = idx - 73728;
    if (i2 >= 0 && i2 < 147456) {
        const int j = i2 & 7;
        const int n = (i2 >> 3) & 127;
        int ky, kx, ci;
        if (i2 < 65536) {
            const int k = (i2 >> 10) * 8 + j;            // 0..511
            ky = (k >> 8) ? 0 : 2;
            kx = ((k >> 7) & 1) ? 0 : 2;
            ci = k & 127;
        } else if (i2 < 98304) {
            const int k = ((i2 - 65536) >> 10) * 8 + j;  // 0..255
            ky = 1;
            kx = (k >> 7) ? 0 : 2;
            ci = k & 127;
        } else if (i2 < 131072) {
            const int k = ((i2 - 98304) >> 10) * 8 + j;  // 0..255
            ky = (k >> 7) ? 0 : 2;
            kx = 1;
            ci = k & 127;
        } else {
            const int k = ((i2 - 131072) >> 10) * 8 + j; // 0..127
            ky = 1; kx = 1;
            ci = k & 127;
        }
        WB[i2] = f2bf(w_up[((ci * COUT + n) * 3 + ky) * 3 + kx]);
    }
    const int i3 = idx - 221184;
    if (i3 >= 0 && i3 < 18432) {
        const int j = i3 & 7;
        const int n = (i3 >> 3) & 31;
        const int g = i3 >> 8;              // 0..71 = s*4 + kg
        const int kg = g & 3, s = g >> 2;
        const int c  = (s & 1) * 32 + kg * 8 + j;
        const int kk = s >> 1;
        const int ki = kk / 3, kj = kk - 3 * ki;
        WOF[i3] = (n < NOFF) ? f2bf(w_off[((n * CIN + c) * 3 + ki) * 3 + kj]) : (unsigned short)0;
    }
}

// ---------------- x transpose to channel-last bf16: xt[b][h][w][c] ----------------
__global__ __launch_bounds__(256) void k_xt(const float* __restrict__ x, unsigned short* __restrict__ xt)
{
    __shared__ unsigned short t[64][66];
    const int tid = threadIdx.x;
    const int h = blockIdx.x & 63, b = blockIdx.x >> 6;
    const int w = tid & 63, cq = tid >> 6;
    #pragma unroll
    for (int p = 0; p < 16; ++p) {
        const int c = p * 4 + cq;
        t[w][c] = f2bf(x[((size_t)((b * 64 + c) * 64) + h) * 64 + w]);
    }
    __syncthreads();
    const int w2 = tid >> 2, q = tid & 3;
    unsigned int pk[8];
    #pragma unroll
    for (int m = 0; m < 8; ++m)
        pk[m] = (unsigned int)t[w2][q * 16 + 2 * m] | ((unsigned int)t[w2][q * 16 + 2 * m + 1] << 16);
    uint4* dst = (uint4*)(xt + ((size_t)((b * 64 + h) * 64) + w2) * 64 + q * 16);
    dst[0] = uint4{pk[0], pk[1], pk[2], pk[3]};
    dst[1] = uint4{pk[4], pk[5], pk[6], pk[7]};
}

// ---------------- offset conv via MFMA, 1 wave per (b, h) ----------------
// M = 64 pixels (w), N = 32 (18 valid oc), K = 576 (kk*64 + c)
__global__ __launch_bounds__(64) void k_offset_mfma(
    const unsigned short* __restrict__ xt, const unsigned short* __restrict__ WOF,
    const float* __restrict__ b_off, float* __restrict__ offs)
{
    const int l  = threadIdx.x;
    const int ml = l & 15;
    const int kg = l >> 4;
    const int h  = blockIdx.x & 63;
    const int b  = blockIdx.x >> 6;
    const unsigned short* xb = xt + (size_t)b * (IH * IW * CIN);

    const f32x4 fz = {0.f, 0.f, 0.f, 0.f};
    f32x4 acc[4][2];
    #pragma unroll
    for (int mt = 0; mt < 4; ++mt) { acc[mt][0] = fz; acc[mt][1] = fz; }

    #pragma unroll 1
    for (int s = 0; s < 18; ++s) {
        const int kk = s >> 1;
        const int ki = kk / 3, kj = kk - 3 * ki;
        const int c0 = (s & 1) * 32 + kg * 8;
        const int yy = h - PADC + ki;
        const bf16x8 b0 = *(const bf16x8*)(WOF + (size_t)(((s * 4 + kg) * 32 + ml) * 8));
        const bf16x8 b1 = *(const bf16x8*)(WOF + (size_t)(((s * 4 + kg) * 32 + 16 + ml) * 8));
        #pragma unroll
        for (int mt = 0; mt < 4; ++mt) {
            const int w  = mt * 16 + ml;
            const int xx = w - PADC + kj;
            bf16x8 a = {0, 0, 0, 0, 0, 0, 0, 0};
            if (yy >= 0 && yy < IH && xx >= 0 && xx < IW)
                a = *(const bf16x8*)(xb + (size_t)((yy * IW + xx) * CIN) + c0);
            acc[mt][0] = __builtin_amdgcn_mfma_f32_16x16x32_bf16(a, b0, acc[mt][0], 0, 0, 0);
            acc[mt][1] = __builtin_amdgcn_mfma_f32_16x16x32_bf16(a, b1, acc[mt][1], 0, 0, 0);
        }
    }
    // D: row = mt*16 + kg*4 + j (pixel w), col = nt*16 + ml (oc)
    #pragma unroll
    for (int nt = 0; nt < 2; ++nt) {
        const int oc = nt * 16 + ml;
        if (oc < NOFF) {
            const float bias = b_off[oc];
            #pragma unroll
            for (int mt = 0; mt < 4; ++mt)
                #pragma unroll
                for (int j = 0; j < 4; ++j) {
                    const int w = mt * 16 + kg * 4 + j;
                    offs[((size_t)(b * NOFF + oc) * IH + h) * IW + w] = acc[mt][nt][j] + bias;
                }
        }
    }
}

// ---------------- deformable conv via MFMA, 1 wave per (b, row) ----------------
__global__ __launch_bounds__(64, 2) void k_deform_mfma(
    const unsigned short* __restrict__ xt, const float* __restrict__ offs,
    const unsigned short* __restrict__ WDF, const float* __restrict__ b_def,
    unsigned short* __restrict__ feats_bf)
{
    const int l  = threadIdx.x;
    const int ml = l & 15;
    const int kg = l >> 4;
    const int h  = blockIdx.x & 63;
    const int b  = blockIdx.x >> 6;

    const unsigned short* xb = xt + (size_t)b * (IH * IW * CIN);

    f32x4 acc[4][8];
    const f32x4 fz = {0.f, 0.f, 0.f, 0.f};
    #pragma unroll
    for (int mt = 0; mt < 4; ++mt)
        #pragma unroll
        for (int nt = 0; nt < 8; ++nt) acc[mt][nt] = fz;

    #pragma unroll 1
    for (int kk = 0; kk < 9; ++kk) {
        const int ki = kk / 3, kj = kk - 3 * ki;
        int   cidx[4][4];
        float cwgt[4][4];
        #pragma unroll
        for (int mt = 0; mt < 4; ++mt) {
            const int w = mt * 16 + ml;
            const float dy = offs[((b * NOFF + 2 * kk) * IH + h) * IW + w];
            const float dx = offs[((b * NOFF + 2 * kk + 1) * IH + h) * IW + w];
            const float py = (float)(h - PADC + ki) + dy;
            const float px = (float)(w - PADC + kj) + dx;
            const float y0f = floorf(py), x0f = floorf(px);
            const float ly = py - y0f, lx = px - x0f;
            const int y0 = (int)y0f, x0 = (int)x0f;
            const float wy[2] = {1.f - ly, ly};
            const float wx[2] = {1.f - lx, lx};
            #pragma unroll
            for (int cy = 0; cy < 2; ++cy)
                #pragma unroll
                for (int cx = 0; cx < 2; ++cx) {
                    const int yy = y0 + cy, xx = x0 + cx;
                    const bool v = (yy >= 0) & (yy < IH) & (xx >= 0) & (xx < IW);
                    cidx[mt][cy * 2 + cx] = v ? ((yy * IW + xx) * CIN) : -1;
                    cwgt[mt][cy * 2 + cx] = wy[cy] * wx[cx];
                }
        }
        #pragma unroll
        for (int ks = 0; ks < 2; ++ks) {
            bf16x8 bfr[8];
            #pragma unroll
            for (int nt = 0; nt < 8; ++nt)
                bfr[nt] = *(const bf16x8*)(WDF + ((size_t)((kk * 8 + ks * 4 + kg) * 128) + nt * 16 + ml) * 8);
            const int c0 = ks * 32 + kg * 8;
            #pragma unroll
            for (int mt = 0; mt < 4; ++mt) {
                float sf[8] = {0.f, 0.f, 0.f, 0.f, 0.f, 0.f, 0.f, 0.f};
                #pragma unroll
                for (int cp = 0; cp < 4; ++cp) {
                    const int ii = cidx[mt][cp];
                    const float wg = cwgt[mt][cp];
                    if (ii >= 0) {
                        const uint4 v = *(const uint4*)(xb + ii + c0);
                        const unsigned int u0 = v.x, u1 = v.y, u2 = v.z, u3 = v.w;
                        sf[0] += wg * __uint_as_float(u0 << 16);
                        sf[1] += wg * __uint_as_float(u0 & 0xFFFF0000u);
                        sf[2] += wg * __uint_as_float(u1 << 16);
                        sf[3] += wg * __uint_as_float(u1 & 0xFFFF0000u);
                        sf[4] += wg * __uint_as_float(u2 << 16);
                        sf[5] += wg * __uint_as_float(u2 & 0xFFFF0000u);
                        sf[6] += wg * __uint_as_float(u3 << 16);
                        sf[7] += wg * __uint_as_float(u3 & 0xFFFF0000u);
                    }
                }
                union { unsigned short us[8]; bf16x8 v; } pa;
                #pragma unroll
                for (int j = 0; j < 8; ++j) pa.us[j] = f2bf(sf[j]);
                #pragma unroll
                for (int nt = 0; nt < 8; ++nt)
                    acc[mt][nt] = __builtin_amdgcn_mfma_f32_16x16x32_bf16(pa.v, bfr[nt], acc[mt][nt], 0, 0, 0);
            }
        }
    }
    #pragma unroll
    for (int nt = 0; nt < 8; ++nt) {
        const int o = nt * 16 + ml;
        const float bias = b_def[o];
        #pragma unroll
        for (int mt = 0; mt < 4; ++mt) {
            #pragma unroll
            for (int j = 0; j < 4; ++j) {
                const int w = mt * 16 + kg * 4 + j;
                feats_bf[((size_t)((b * IH + h) * IW) + w) * COUT + o] = f2bf(acc[mt][nt][j] + bias);
            }
        }
    }
}

// ---------------- convT via MFMA + fused BN partial stats (no b_up: cancels in BN) ----------------
__global__ __launch_bounds__(256) void k_convT_mfma(
    const unsigned short* __restrict__ feats_bf, const unsigned short* __restrict__ WB,
    float* __restrict__ y, float* __restrict__ partials)
{
    __shared__ __align__(16) char smem[34048];   // 2*16896 rows / 4*8512 slabs (union)

    const int tid = threadIdx.x;
    const int l   = tid & 63;
    const int wv  = tid >> 6;
    const int ml  = l & 15;
    const int kg  = l >> 4;
    const int blk = blockIdx.x;
    const int oy  = blk % OYX;
    const int b   = blk / OYX;
    const int py  = oy & 1;
    const int ty  = oy >> 1;

    const int nrow = py ? 1 : 2;
    int iys[2];
    if (py == 0) { iys[0] = ty - 1; iys[1] = (ty <= 63) ? ty : -1; }
    else         { iys[0] = ty;     iys[1] = -1; }

    for (int r = 0; r < nrow; ++r) {
        char* dstbase = smem + r * 16896;
        const int iy = iys[r];
        if (iy < 0 || iy > 63) {
            for (int i = tid; i < 1056; i += 256)
                *(uint4*)(dstbase + i * 16) = uint4{0, 0, 0, 0};
        } else {
            const unsigned short* src = feats_bf + (size_t)(b * IH + iy) * (IW * COUT);
            for (int i = tid; i < 1024; i += 256) {
                const uint4 v = *(const uint4*)(src + i * 8);
                const int G = 16 + i;
                const int phys = G ^ ((G >> 4) & 7);
                *(uint4*)(dstbase + phys * 16) = v;
            }
            if (tid < 32) {
                const int G = (tid < 16) ? tid : (1024 + tid);
                const int phys = G ^ ((G >> 4) & 7);
                *(uint4*)(dstbase + phys * 16) = uint4{0, 0, 0, 0};
            }
        }
    }
    __syncthreads();

    const f32x4 fz = {0.f, 0.f, 0.f, 0.f};
    f32x4 acc0[5][2], acc1[4][2];
    #pragma unroll
    for (int m = 0; m < 5; ++m) { acc0[m][0] = fz; acc0[m][1] = fz; }
    #pragma unroll
    for (int m = 0; m < 4; ++m) { acc1[m][0] = fz; acc1[m][1] = fz; }

    const int n0   = wv * 32;
    const int nK0  = py ? 8 : 16;
    const int nK1  = py ? 4 : 8;
    const unsigned short* segG0 = WB + (py ? 65536 : 0);
    const unsigned short* segG1 = WB + (py ? 131072 : 98304);

    for (int ks = 0; ks < nK0; ++ks) {
        const int kk   = ks * 32 + kg * 8;
        const int slot = kk >> 8;
        const int kb   = (kk & 255) >> 3;
        const bf16x8 b0 = *(const bf16x8*)(segG0 + ((ks * 4 + kg) * 128 + n0 + ml) * 8);
        const bf16x8 b1 = *(const bf16x8*)(segG0 + ((ks * 4 + kg) * 128 + n0 + 16 + ml) * 8);
        #pragma unroll
        for (int mt = 0; mt < 5; ++mt) {
            int tx = mt * 16 + ml; if (tx > 64) tx = 64;
            const int G = tx * 16 + kb;
            const int phys = G ^ ((G >> 4) & 7);
            const bf16x8 a = *(const bf16x8*)(smem + slot * 16896 + phys * 16);
            acc0[mt][0] = __builtin_amdgcn_mfma_f32_16x16x32_bf16(a, b0, acc0[mt][0], 0, 0, 0);
            acc0[mt][1] = __builtin_amdgcn_mfma_f32_16x16x32_bf16(a, b1, acc0[mt][1], 0, 0, 0);
        }
    }
    for (int ks = 0; ks < nK1; ++ks) {
        const int kk   = ks * 32 + kg * 8;
        const int slot = kk >> 7;
        const int kb   = (kk & 127) >> 3;
        const bf16x8 b0 = *(const bf16x8*)(segG1 + ((ks * 4 + kg) * 128 + n0 + ml) * 8);
        const bf16x8 b1 = *(const bf16x8*)(segG1 + ((ks * 4 + kg) * 128 + n0 + 16 + ml) * 8);
        #pragma unroll
        for (int mt = 0; mt < 4; ++mt) {
            const int tx = mt * 16 + ml;
            const int G = 16 + tx * 16 + kb;
            const int phys = G ^ ((G >> 4) & 7);
            const bf16x8 a = *(const bf16x8*)(smem + slot * 16896 + phys * 16);
            acc1[mt][0] = __builtin_amdgcn_mfma_f32_16x16x32_bf16(a, b0, acc1[mt][0], 0, 0, 0);
            acc1[mt][1] = __builtin_amdgcn_mfma_f32_16x16x32_bf16(a, b1, acc1[mt][1], 0, 0, 0);
        }
    }

    __syncthreads();
    float* slab = (float*)smem + wv * 2128;   // [16 co][133 ox]
    const int rrow = kg * 4;
    #pragma unroll
    for (int nt = 0; nt < 2; ++nt) {
        #pragma unroll
        for (int mt = 0; mt < 5; ++mt) {
            #pragma unroll
            for (int j = 0; j < 4; ++j) {
                const int tx = mt * 16 + rrow + j;
                if (tx <= 64) slab[ml * 133 + 2 * tx] = acc0[mt][nt][j];
            }
        }
        #pragma unroll
        for (int mt = 0; mt < 4; ++mt) {
            #pragma unroll
            for (int j = 0; j < 4; ++j) {
                const int tx = mt * 16 + rrow + j;
                slab[ml * 133 + 2 * tx + 1] = acc1[mt][nt][j];
            }
        }
        __syncthreads();
        // store y (no bias — cancels in BN)
        #pragma unroll
        for (int r2 = 0; r2 < 16; ++r2) {
            const int co = n0 + nt * 16 + r2;
            float* drow = y + ((size_t)(b * COUT + co) * OYX + oy) * OYX;
            drow[l]      = slab[r2 * 133 + l];
            drow[64 + l] = slab[r2 * 133 + 64 + l];
            if (l == 0) drow[128] = slab[r2 * 133 + 128];
        }
        // fused BN partials: lane-per-co-row column sums, 4-lane reduce
        {
            const int r = ml;          // co row 0..15
            const int g = kg;          // column group 0..3
            float s = 0.f, q = 0.f;
            #pragma unroll
            for (int t = 0; t < 33; ++t) {
                const int cx = g + 4 * t;
                if (cx < 129) {
                    const float v = slab[r * 133 + cx];
                    s += v; q += v * v;
                }
            }
            s += __shfl_xor(s, 16, 64); q += __shfl_xor(q, 16, 64);
            s += __shfl_xor(s, 32, 64); q += __shfl_xor(q, 32, 64);
            if (kg == 0) {
                float* pp = partials + ((size_t)blk * COUT + n0 + nt * 16 + ml) * 2;
                pp[0] = s; pp[1] = q;
            }
        }
        __syncthreads();
    }
}

// ---------------- BN finalize: reduce per-block partials ----------------
__global__ __launch_bounds__(256) void k_bn_final(const float* __restrict__ partials,
                                                  float* __restrict__ stats)
{
    const int c = blockIdx.x;      // 128
    const int tid = threadIdx.x;
    float s = 0.f, q = 0.f;
    for (int i = tid; i < NBLK_CT; i += 256) {
        const float* pp = partials + ((size_t)i * COUT + c) * 2;
        s += pp[0]; q += pp[1];
    }
    __shared__ float rs[256], rq[256];
    rs[tid] = s; rq[tid] = q;
    __syncthreads();
    for (int off = 128; off > 0; off >>= 1) {
        if (tid < off) { rs[tid] += rs[tid + off]; rq[tid] += rq[tid + off]; }
        __syncthreads();
    }
    if (tid == 0) {
        const float n = (float)(NB * SPO);
        const float mean = rs[0] / n;
        const float var  = rq[0] / n - mean * mean;
        stats[c] = mean;
        stats[COUT + c] = rsqrtf(var + BNEPS);
    }
}

// ---------------- BN apply + ReLU (in place on d_out) ----------------
__global__ void k_bn_apply(float* __restrict__ y, const float* __restrict__ stats,
                           const float* __restrict__ gamma, const float* __restrict__ beta)
{
    const int i = blockIdx.x * 256 + threadIdx.x;
    const int c = (i / SPO) & (COUT - 1);
    const float mean = stats[c], rstd = stats[COUT + c];
    float v = y[i];
    v = (v - mean) * rstd * gamma[c] + beta[c];
    y[i] = fmaxf(v, 0.f);
}

extern "C" void kernel_launch(void* const* d_in, const int* in_sizes, int n_in,
                              void* d_out, int out_size, void* d_ws, size_t ws_size,
                              hipStream_t stream)
{
    const float* x     = (const float*)d_in[0];
    const float* w_off = (const float*)d_in[1];
    const float* b_off = (const float*)d_in[2];
    const float* w_def = (const float*)d_in[3];
    const float* b_def = (const float*)d_in[4];
    const float* w_up  = (const float*)d_in[5];
    const float* b_up  = (const float*)d_in[6];  (void)b_up;  // cancels in BN
    const float* gamma = (const float*)d_in[7];
    const float* beta  = (const float*)d_in[8];
    float* y = (float*)d_out;

    float* ws       = (float*)d_ws;
    float* offs     = ws;                     // 1,179,648 f32
    float* stats    = offs + 1179648;         //       256 f32
    float* partials = stats + 256;            //   528,384 f32
    unsigned short* xt       = (unsigned short*)(partials + 528384);  // 4,194,304 bf16
    unsigned short* WDF      = xt + 4194304;                          //    73,728 bf16
    unsigned short* feats_bf = WDF + 73728;                           // 8,388,608 bf16
    unsigned short* WB       = feats_bf + 8388608;                    //   147,456 bf16
    unsigned short* WOF      = WB + 147456;                           //    18,432 bf16

    k_prep        <<<dim3(936),    dim3(256), 0, stream>>>(w_def, w_up, w_off, WDF, WB, WOF);
    k_xt          <<<dim3(1024),   dim3(256), 0, stream>>>(x, xt);
    k_offset_mfma <<<dim3(1024),   dim3(64),  0, stream>>>(xt, WOF, b_off, offs);
    k_deform_mfma <<<dim3(1024),   dim3(64),  0, stream>>>(xt, offs, WDF, b_def, feats_bf);
    k_convT_mfma  <<<dim3(NBLK_CT),dim3(256), 0, stream>>>(feats_bf, WB, y, partials);
    k_bn_final    <<<dim3(128),    dim3(256), 0, stream>>>(partials, stats);
    k_bn_apply    <<<dim3(133128), dim3(256), 0, stream>>>(y, stats, gamma, beta);
}

// Round 6
// 201.523 us; speedup vs baseline: 8.0836x; 1.3637x over previous
//
#include <hip/hip_runtime.h>
#include <math.h>

#define PADC 1
#define CIN  64
#define COUT 128
#define IH   64
#define IW   64
#define NB   16
#define OYX  129
#define NOFF 18
#define SPO  (OYX * OYX)   // 16641
#define BNEPS 1e-5f
#define NBLK_CT (NB * OYX) // 2064 convT blocks

typedef __attribute__((ext_vector_type(8))) short bf16x8;
typedef __attribute__((ext_vector_type(4))) float f32x4;

static __device__ __forceinline__ unsigned short f2bf(float f) {
    unsigned int b = __float_as_uint(f);
    unsigned int r = (b + 0x7FFFu + ((b >> 16) & 1u)) >> 16;   // RNE
    return (unsigned short)r;
}

// ---------------- weight prep ----------------
// WDF: deform weights B-frag order (73728)
// WB : convT weights, 4 segments (147456)
// WOF: offset-conv weights B-frag order, N padded 18->32 (18432)
__global__ void k_prep(const float* __restrict__ w_def, const float* __restrict__ w_up,
                       const float* __restrict__ w_off,
                       unsigned short* __restrict__ WDF, unsigned short* __restrict__ WB,
                       unsigned short* __restrict__ WOF)
{
    int idx = blockIdx.x * 256 + threadIdx.x;
    if (idx < 73728) {
        const int j = idx & 7;
        const int n = (idx >> 3) & 127;
        const int g = idx >> 10;            // 0..71 = kk*8 + ks*4 + kg
        const int kg = g & 3, ks = (g >> 2) & 1, kk = g >> 3;
        const int c = ks * 32 + kg * 8 + j;
        WDF[idx] = f2bf(w_def[(n * CIN + c) * 9 + kk]);
    }
    const int i2 = idx - 73728;
    if (i2 >= 0 && i2 < 147456) {
        const int j = i2 & 7;
        const int n = (i2 >> 3) & 127;
        int ky, kx, ci;
        if (i2 < 65536) {
            const int k = (i2 >> 10) * 8 + j;            // 0..511
            ky = (k >> 8) ? 0 : 2;
            kx = ((k >> 7) & 1) ? 0 : 2;
            ci = k & 127;
        } else if (i2 < 98304) {
            const int k = ((i2 - 65536) >> 10) * 8 + j;  // 0..255
            ky = 1;
            kx = (k >> 7) ? 0 : 2;
            ci = k & 127;
        } else if (i2 < 131072) {
            const int k = ((i2 - 98304) >> 10) * 8 + j;  // 0..255
            ky = (k >> 7) ? 0 : 2;
            kx = 1;
            ci = k & 127;
        } else {
            const int k = ((i2 - 131072) >> 10) * 8 + j; // 0..127
            ky = 1; kx = 1;
            ci = k & 127;
        }
        WB[i2] = f2bf(w_up[((ci * COUT + n) * 3 + ky) * 3 + kx]);
    }
    const int i3 = idx - 221184;
    if (i3 >= 0 && i3 < 18432) {
        const int j = i3 & 7;
        const int n = (i3 >> 3) & 31;
        const int g = i3 >> 8;              // 0..71 = s*4 + kg
        const int kg = g & 3, s = g >> 2;
        const int c  = (s & 1) * 32 + kg * 8 + j;
        const int kk = s >> 1;
        const int ki = kk / 3, kj = kk - 3 * ki;
        WOF[i3] = (n < NOFF) ? f2bf(w_off[((n * CIN + c) * 3 + ki) * 3 + kj]) : (unsigned short)0;
    }
}

// ---------------- x transpose to channel-last bf16: xt[b][h][w][c] ----------------
__global__ __launch_bounds__(256) void k_xt(const float* __restrict__ x, unsigned short* __restrict__ xt)
{
    __shared__ unsigned short t[64][66];
    const int tid = threadIdx.x;
    const int h = blockIdx.x & 63, b = blockIdx.x >> 6;
    const int w = tid & 63, cq = tid >> 6;
    #pragma unroll
    for (int p = 0; p < 16; ++p) {
        const int c = p * 4 + cq;
        t[w][c] = f2bf(x[((size_t)((b * 64 + c) * 64) + h) * 64 + w]);
    }
    __syncthreads();
    const int w2 = tid >> 2, q = tid & 3;
    unsigned int pk[8];
    #pragma unroll
    for (int m = 0; m < 8; ++m)
        pk[m] = (unsigned int)t[w2][q * 16 + 2 * m] | ((unsigned int)t[w2][q * 16 + 2 * m + 1] << 16);
    uint4* dst = (uint4*)(xt + ((size_t)((b * 64 + h) * 64) + w2) * 64 + q * 16);
    dst[0] = uint4{pk[0], pk[1], pk[2], pk[3]};
    dst[1] = uint4{pk[4], pk[5], pk[6], pk[7]};
}

// ---------------- offset conv via MFMA, 1 wave per (b, h, quarter) ----------------
// M = 16 pixels, N = 32 (18 valid oc), K = 576
__global__ __launch_bounds__(64, 4) void k_offset_mfma(
    const unsigned short* __restrict__ xt, const unsigned short* __restrict__ WOF,
    const float* __restrict__ b_off, float* __restrict__ offs)
{
    const int l  = threadIdx.x;
    const int ml = l & 15;
    const int kg = l >> 4;
    const int q  = blockIdx.x & 3;
    const int h  = (blockIdx.x >> 2) & 63;
    const int b  = blockIdx.x >> 8;
    const int w  = q * 16 + ml;
    const unsigned short* xb = xt + (size_t)b * (IH * IW * CIN);

    const f32x4 fz = {0.f, 0.f, 0.f, 0.f};
    f32x4 acc0 = fz, acc1 = fz;

    #pragma unroll 1
    for (int s = 0; s < 18; ++s) {
        const int kk = s >> 1;
        const int ki = kk / 3, kj = kk - 3 * ki;
        const int c0 = (s & 1) * 32 + kg * 8;
        const int yy = h - PADC + ki;
        const int xx = w - PADC + kj;
        const bf16x8 b0 = *(const bf16x8*)(WOF + (size_t)(((s * 4 + kg) * 32 + ml) * 8));
        const bf16x8 b1 = *(const bf16x8*)(WOF + (size_t)(((s * 4 + kg) * 32 + 16 + ml) * 8));
        bf16x8 a = {0, 0, 0, 0, 0, 0, 0, 0};
        if (yy >= 0 && yy < IH && xx >= 0 && xx < IW)
            a = *(const bf16x8*)(xb + (size_t)((yy * IW + xx) * CIN) + c0);
        acc0 = __builtin_amdgcn_mfma_f32_16x16x32_bf16(a, b0, acc0, 0, 0, 0);
        acc1 = __builtin_amdgcn_mfma_f32_16x16x32_bf16(a, b1, acc1, 0, 0, 0);
    }
    // D: row = kg*4 + j (pixel within quarter), col = nt*16 + ml (oc)
    #pragma unroll
    for (int nt = 0; nt < 2; ++nt) {
        const int oc = nt * 16 + ml;
        if (oc < NOFF) {
            const float bias = b_off[oc];
            const f32x4 av = nt ? acc1 : acc0;
            #pragma unroll
            for (int j = 0; j < 4; ++j) {
                const int wd = q * 16 + kg * 4 + j;
                offs[((size_t)(b * NOFF + oc) * IH + h) * IW + wd] = av[j] + bias;
            }
        }
    }
}

// ---------------- deformable conv via MFMA, 1 wave per (b, h, quarter) ----------------
__global__ __launch_bounds__(64, 4) void k_deform_mfma(
    const unsigned short* __restrict__ xt, const float* __restrict__ offs,
    const unsigned short* __restrict__ WDF, const float* __restrict__ b_def,
    unsigned short* __restrict__ feats_bf)
{
    const int l  = threadIdx.x;
    const int ml = l & 15;
    const int kg = l >> 4;
    const int q  = blockIdx.x & 3;
    const int h  = (blockIdx.x >> 2) & 63;
    const int b  = blockIdx.x >> 8;
    const int w  = q * 16 + ml;

    const unsigned short* xb = xt + (size_t)b * (IH * IW * CIN);

    const f32x4 fz = {0.f, 0.f, 0.f, 0.f};
    f32x4 acc[8];
    #pragma unroll
    for (int nt = 0; nt < 8; ++nt) acc[nt] = fz;

    #pragma unroll 1
    for (int kk = 0; kk < 9; ++kk) {
        const int ki = kk / 3, kj = kk - 3 * ki;
        const float dy = offs[((b * NOFF + 2 * kk) * IH + h) * IW + w];
        const float dx = offs[((b * NOFF + 2 * kk + 1) * IH + h) * IW + w];
        const float py = (float)(h - PADC + ki) + dy;
        const float px = (float)(w - PADC + kj) + dx;
        const float y0f = floorf(py), x0f = floorf(px);
        const float ly = py - y0f, lx = px - x0f;
        const int y0 = (int)y0f, x0 = (int)x0f;
        const float wy[2] = {1.f - ly, ly};
        const float wx[2] = {1.f - lx, lx};
        int   cidx[4];
        float cwgt[4];
        #pragma unroll
        for (int cy = 0; cy < 2; ++cy)
            #pragma unroll
            for (int cx = 0; cx < 2; ++cx) {
                const int yy = y0 + cy, xx = x0 + cx;
                const bool v = (yy >= 0) & (yy < IH) & (xx >= 0) & (xx < IW);
                cidx[cy * 2 + cx] = v ? ((yy * IW + xx) * CIN) : 0;       // branchless: clamp addr
                cwgt[cy * 2 + cx] = v ? (wy[cy] * wx[cx]) : 0.f;         // kill via weight
            }
        #pragma unroll
        for (int ks = 0; ks < 2; ++ks) {
            const int c0 = ks * 32 + kg * 8;
            // issue all 4 corner loads + 8 B-frag loads unconditionally (MLP)
            uint4 cv[4];
            #pragma unroll
            for (int cp = 0; cp < 4; ++cp)
                cv[cp] = *(const uint4*)(xb + cidx[cp] + c0);
            bf16x8 bfr[8];
            #pragma unroll
            for (int nt = 0; nt < 8; ++nt)
                bfr[nt] = *(const bf16x8*)(WDF + ((size_t)((kk * 8 + ks * 4 + kg) * 128) + nt * 16 + ml) * 8);
            float sf[8] = {0.f, 0.f, 0.f, 0.f, 0.f, 0.f, 0.f, 0.f};
            #pragma unroll
            for (int cp = 0; cp < 4; ++cp) {
                const float wg = cwgt[cp];
                const unsigned int u0 = cv[cp].x, u1 = cv[cp].y, u2 = cv[cp].z, u3 = cv[cp].w;
                sf[0] += wg * __uint_as_float(u0 << 16);
                sf[1] += wg * __uint_as_float(u0 & 0xFFFF0000u);
                sf[2] += wg * __uint_as_float(u1 << 16);
                sf[3] += wg * __uint_as_float(u1 & 0xFFFF0000u);
                sf[4] += wg * __uint_as_float(u2 << 16);
                sf[5] += wg * __uint_as_float(u2 & 0xFFFF0000u);
                sf[6] += wg * __uint_as_float(u3 << 16);
                sf[7] += wg * __uint_as_float(u3 & 0xFFFF0000u);
            }
            union { unsigned short us[8]; bf16x8 v; } pa;
            #pragma unroll
            for (int j = 0; j < 8; ++j) pa.us[j] = f2bf(sf[j]);
            #pragma unroll
            for (int nt = 0; nt < 8; ++nt)
                acc[nt] = __builtin_amdgcn_mfma_f32_16x16x32_bf16(pa.v, bfr[nt], acc[nt], 0, 0, 0);
        }
    }
    // epilogue: D row = kg*4 + j (pixel), col = nt*16 + ml (channel o)
    #pragma unroll
    for (int nt = 0; nt < 8; ++nt) {
        const int o = nt * 16 + ml;
        const float bias = b_def[o];
        #pragma unroll
        for (int j = 0; j < 4; ++j) {
            const int wd = q * 16 + kg * 4 + j;
            feats_bf[((size_t)((b * IH + h) * IW) + wd) * COUT + o] = f2bf(acc[nt][j] + bias);
        }
    }
}

// ---------------- convT via MFMA + fused BN partial stats (no b_up: cancels in BN) ----------------
__global__ __launch_bounds__(256) void k_convT_mfma(
    const unsigned short* __restrict__ feats_bf, const unsigned short* __restrict__ WB,
    float* __restrict__ y, float* __restrict__ partials)
{
    __shared__ __align__(16) char smem[34048];   // 2*16896 rows / 4*8512 slabs (union)

    const int tid = threadIdx.x;
    const int l   = tid & 63;
    const int wv  = tid >> 6;
    const int ml  = l & 15;
    const int kg  = l >> 4;
    const int blk = blockIdx.x;
    const int oy  = blk % OYX;
    const int b   = blk / OYX;
    const int py  = oy & 1;
    const int ty  = oy >> 1;

    const int nrow = py ? 1 : 2;
    int iys[2];
    if (py == 0) { iys[0] = ty - 1; iys[1] = (ty <= 63) ? ty : -1; }
    else         { iys[0] = ty;     iys[1] = -1; }

    for (int r = 0; r < nrow; ++r) {
        char* dstbase = smem + r * 16896;
        const int iy = iys[r];
        if (iy < 0 || iy > 63) {
            for (int i = tid; i < 1056; i += 256)
                *(uint4*)(dstbase + i * 16) = uint4{0, 0, 0, 0};
        } else {
            const unsigned short* src = feats_bf + (size_t)(b * IH + iy) * (IW * COUT);
            for (int i = tid; i < 1024; i += 256) {
                const uint4 v = *(const uint4*)(src + i * 8);
                const int G = 16 + i;
                const int phys = G ^ ((G >> 4) & 7);
                *(uint4*)(dstbase + phys * 16) = v;
            }
            if (tid < 32) {
                const int G = (tid < 16) ? tid : (1024 + tid);
                const int phys = G ^ ((G >> 4) & 7);
                *(uint4*)(dstbase + phys * 16) = uint4{0, 0, 0, 0};
            }
        }
    }
    __syncthreads();

    const f32x4 fz = {0.f, 0.f, 0.f, 0.f};
    f32x4 acc0[5][2], acc1[4][2];
    #pragma unroll
    for (int m = 0; m < 5; ++m) { acc0[m][0] = fz; acc0[m][1] = fz; }
    #pragma unroll
    for (int m = 0; m < 4; ++m) { acc1[m][0] = fz; acc1[m][1] = fz; }

    const int n0   = wv * 32;
    const int nK0  = py ? 8 : 16;
    const int nK1  = py ? 4 : 8;
    const unsigned short* segG0 = WB + (py ? 65536 : 0);
    const unsigned short* segG1 = WB + (py ? 131072 : 98304);

    for (int ks = 0; ks < nK0; ++ks) {
        const int kk   = ks * 32 + kg * 8;
        const int slot = kk >> 8;
        const int kb   = (kk & 255) >> 3;
        const bf16x8 b0 = *(const bf16x8*)(segG0 + ((ks * 4 + kg) * 128 + n0 + ml) * 8);
        const bf16x8 b1 = *(const bf16x8*)(segG0 + ((ks * 4 + kg) * 128 + n0 + 16 + ml) * 8);
        #pragma unroll
        for (int mt = 0; mt < 5; ++mt) {
            int tx = mt * 16 + ml; if (tx > 64) tx = 64;
            const int G = tx * 16 + kb;
            const int phys = G ^ ((G >> 4) & 7);
            const bf16x8 a = *(const bf16x8*)(smem + slot * 16896 + phys * 16);
            acc0[mt][0] = __builtin_amdgcn_mfma_f32_16x16x32_bf16(a, b0, acc0[mt][0], 0, 0, 0);
            acc0[mt][1] = __builtin_amdgcn_mfma_f32_16x16x32_bf16(a, b1, acc0[mt][1], 0, 0, 0);
        }
    }
    for (int ks = 0; ks < nK1; ++ks) {
        const int kk   = ks * 32 + kg * 8;
        const int slot = kk >> 7;
        const int kb   = (kk & 127) >> 3;
        const bf16x8 b0 = *(const bf16x8*)(segG1 + ((ks * 4 + kg) * 128 + n0 + ml) * 8);
        const bf16x8 b1 = *(const bf16x8*)(segG1 + ((ks * 4 + kg) * 128 + n0 + 16 + ml) * 8);
        #pragma unroll
        for (int mt = 0; mt < 4; ++mt) {
            const int tx = mt * 16 + ml;
            const int G = 16 + tx * 16 + kb;
            const int phys = G ^ ((G >> 4) & 7);
            const bf16x8 a = *(const bf16x8*)(smem + slot * 16896 + phys * 16);
            acc1[mt][0] = __builtin_amdgcn_mfma_f32_16x16x32_bf16(a, b0, acc1[mt][0], 0, 0, 0);
            acc1[mt][1] = __builtin_amdgcn_mfma_f32_16x16x32_bf16(a, b1, acc1[mt][1], 0, 0, 0);
        }
    }

    __syncthreads();
    float* slab = (float*)smem + wv * 2128;   // [16 co][133 ox]
    const int rrow = kg * 4;
    #pragma unroll
    for (int nt = 0; nt < 2; ++nt) {
        #pragma unroll
        for (int mt = 0; mt < 5; ++mt) {
            #pragma unroll
            for (int j = 0; j < 4; ++j) {
                const int tx = mt * 16 + rrow + j;
                if (tx <= 64) slab[ml * 133 + 2 * tx] = acc0[mt][nt][j];
            }
        }
        #pragma unroll
        for (int mt = 0; mt < 4; ++mt) {
            #pragma unroll
            for (int j = 0; j < 4; ++j) {
                const int tx = mt * 16 + rrow + j;
                slab[ml * 133 + 2 * tx + 1] = acc1[mt][nt][j];
            }
        }
        __syncthreads();
        // store y (no bias — cancels in BN)
        #pragma unroll
        for (int r2 = 0; r2 < 16; ++r2) {
            const int co = n0 + nt * 16 + r2;
            float* drow = y + ((size_t)(b * COUT + co) * OYX + oy) * OYX;
            drow[l]      = slab[r2 * 133 + l];
            drow[64 + l] = slab[r2 * 133 + 64 + l];
            if (l == 0) drow[128] = slab[r2 * 133 + 128];
        }
        // fused BN partials: lane-per-co-row column sums, 4-lane reduce
        {
            const int r = ml;          // co row 0..15
            const int g = kg;          // column group 0..3
            float s = 0.f, q = 0.f;
            #pragma unroll
            for (int t = 0; t < 33; ++t) {
                const int cx = g + 4 * t;
                if (cx < 129) {
                    const float v = slab[r * 133 + cx];
                    s += v; q += v * v;
                }
            }
            s += __shfl_xor(s, 16, 64); q += __shfl_xor(q, 16, 64);
            s += __shfl_xor(s, 32, 64); q += __shfl_xor(q, 32, 64);
            if (kg == 0) {
                float* pp = partials + ((size_t)blk * COUT + n0 + nt * 16 + ml) * 2;
                pp[0] = s; pp[1] = q;
            }
        }
        __syncthreads();
    }
}

// ---------------- BN finalize: reduce per-block partials ----------------
__global__ __launch_bounds__(256) void k_bn_final(const float* __restrict__ partials,
                                                  float* __restrict__ stats)
{
    const int c = blockIdx.x;      // 128
    const int tid = threadIdx.x;
    float s = 0.f, q = 0.f;
    for (int i = tid; i < NBLK_CT; i += 256) {
        const float* pp = partials + ((size_t)i * COUT + c) * 2;
        s += pp[0]; q += pp[1];
    }
    __shared__ float rs[256], rq[256];
    rs[tid] = s; rq[tid] = q;
    __syncthreads();
    for (int off = 128; off > 0; off >>= 1) {
        if (tid < off) { rs[tid] += rs[tid + off]; rq[tid] += rq[tid + off]; }
        __syncthreads();
    }
    if (tid == 0) {
        const float n = (float)(NB * SPO);
        const float mean = rs[0] / n;
        const float var  = rq[0] / n - mean * mean;
        stats[c] = mean;
        stats[COUT + c] = rsqrtf(var + BNEPS);
    }
}

// ---------------- BN apply + ReLU (in place on d_out) ----------------
__global__ void k_bn_apply(float* __restrict__ y, const float* __restrict__ stats,
                           const float* __restrict__ gamma, const float* __restrict__ beta)
{
    const int i = blockIdx.x * 256 + threadIdx.x;
    const int c = (i / SPO) & (COUT - 1);
    const float mean = stats[c], rstd = stats[COUT + c];
    float v = y[i];
    v = (v - mean) * rstd * gamma[c] + beta[c];
    y[i] = fmaxf(v, 0.f);
}

extern "C" void kernel_launch(void* const* d_in, const int* in_sizes, int n_in,
                              void* d_out, int out_size, void* d_ws, size_t ws_size,
                              hipStream_t stream)
{
    const float* x     = (const float*)d_in[0];
    const float* w_off = (const float*)d_in[1];
    const float* b_off = (const float*)d_in[2];
    const float* w_def = (const float*)d_in[3];
    const float* b_def = (const float*)d_in[4];
    const float* w_up  = (const float*)d_in[5];
    const float* b_up  = (const float*)d_in[6];  (void)b_up;  // cancels in BN
    const float* gamma = (const float*)d_in[7];
    const float* beta  = (const float*)d_in[8];
    float* y = (float*)d_out;

    float* ws       = (float*)d_ws;
    float* offs     = ws;                     // 1,179,648 f32
    float* stats    = offs + 1179648;         //       256 f32
    float* partials = stats + 256;            //   528,384 f32
    unsigned short* xt       = (unsigned short*)(partials + 528384);  // 4,194,304 bf16
    unsigned short* WDF      = xt + 4194304;                          //    73,728 bf16
    unsigned short* feats_bf = WDF + 73728;                           // 8,388,608 bf16
    unsigned short* WB       = feats_bf + 8388608;                    //   147,456 bf16
    unsigned short* WOF      = WB + 147456;                           //    18,432 bf16

    k_prep        <<<dim3(936),    dim3(256), 0, stream>>>(w_def, w_up, w_off, WDF, WB, WOF);
    k_xt          <<<dim3(1024),   dim3(256), 0, stream>>>(x, xt);
    k_offset_mfma <<<dim3(4096),   dim3(64),  0, stream>>>(xt, WOF, b_off, offs);
    k_deform_mfma <<<dim3(4096),   dim3(64),  0, stream>>>(xt, offs, WDF, b_def, feats_bf);
    k_convT_mfma  <<<dim3(NBLK_CT),dim3(256), 0, stream>>>(feats_bf, WB, y, partials);
    k_bn_final    <<<dim3(128),    dim3(256), 0, stream>>>(partials, stats);
    k_bn_apply    <<<dim3(133128), dim3(256), 0, stream>>>(y, stats, gamma, beta);
}

// Round 7
// 198.415 us; speedup vs baseline: 8.2102x; 1.0157x over previous
//
#include <hip/hip_runtime.h>
#include <math.h>

#define PADC 1
#define CIN  64
#define COUT 128
#define IH   64
#define IW   64
#define NB   16
#define OYX  129
#define NOFF 18
#define SPO  (OYX * OYX)   // 16641
#define BNEPS 1e-5f
#define NBLK_CT (NB * OYX) // 2064 convT blocks

typedef __attribute__((ext_vector_type(8))) short bf16x8;
typedef __attribute__((ext_vector_type(4))) float f32x4;

static __device__ __forceinline__ unsigned short f2bf(float f) {
    unsigned int b = __float_as_uint(f);
    unsigned int r = (b + 0x7FFFu + ((b >> 16) & 1u)) >> 16;   // RNE
    return (unsigned short)r;
}
static __device__ __forceinline__ float bf2f(unsigned short u) {
    return __uint_as_float((unsigned int)u << 16);
}

// ---------------- weight prep ----------------
// WDF: deform weights B-frag order (73728)
// WB : convT weights, 4 segments (147456)
// WOF: offset-conv weights B-frag order, N padded 18->32 (18432)
__global__ void k_prep(const float* __restrict__ w_def, const float* __restrict__ w_up,
                       const float* __restrict__ w_off,
                       unsigned short* __restrict__ WDF, unsigned short* __restrict__ WB,
                       unsigned short* __restrict__ WOF)
{
    int idx = blockIdx.x * 256 + threadIdx.x;
    if (idx < 73728) {
        const int j = idx & 7;
        const int n = (idx >> 3) & 127;
        const int g = idx >> 10;            // 0..71 = kk*8 + ks*4 + kg
        const int kg = g & 3, ks = (g >> 2) & 1, kk = g >> 3;
        const int c = ks * 32 + kg * 8 + j;
        WDF[idx] = f2bf(w_def[(n * CIN + c) * 9 + kk]);
    }
    const int i2 = idx - 73728;
    if (i2 >= 0 && i2 < 147456) {
        const int j = i2 & 7;
        const int n = (i2 >> 3) & 127;
        int ky, kx, ci;
        if (i2 < 65536) {
            const int k = (i2 >> 10) * 8 + j;            // 0..511
            ky = (k >> 8) ? 0 : 2;
            kx = ((k >> 7) & 1) ? 0 : 2;
            ci = k & 127;
        } else if (i2 < 98304) {
            const int k = ((i2 - 65536) >> 10) * 8 + j;  // 0..255
            ky = 1;
            kx = (k >> 7) ? 0 : 2;
            ci = k & 127;
        } else if (i2 < 131072) {
            const int k = ((i2 - 98304) >> 10) * 8 + j;  // 0..255
            ky = (k >> 7) ? 0 : 2;
            kx = 1;
            ci = k & 127;
        } else {
            const int k = ((i2 - 131072) >> 10) * 8 + j; // 0..127
            ky = 1; kx = 1;
            ci = k & 127;
        }
        WB[i2] = f2bf(w_up[((ci * COUT + n) * 3 + ky) * 3 + kx]);
    }
    const int i3 = idx - 221184;
    if (i3 >= 0 && i3 < 18432) {
        const int j = i3 & 7;
        const int n = (i3 >> 3) & 31;
        const int g = i3 >> 8;              // 0..71 = s*4 + kg
        const int kg = g & 3, s = g >> 2;
        const int c  = (s & 1) * 32 + kg * 8 + j;
        const int kk = s >> 1;
        const int ki = kk / 3, kj = kk - 3 * ki;
        WOF[i3] = (n < NOFF) ? f2bf(w_off[((n * CIN + c) * 3 + ki) * 3 + kj]) : (unsigned short)0;
    }
}

// ---------------- x transpose to channel-last bf16: xt[b][h][w][c] ----------------
__global__ __launch_bounds__(256) void k_xt(const float* __restrict__ x, unsigned short* __restrict__ xt)
{
    __shared__ unsigned short t[64][66];
    const int tid = threadIdx.x;
    const int h = blockIdx.x & 63, b = blockIdx.x >> 6;
    const int w = tid & 63, cq = tid >> 6;
    #pragma unroll
    for (int p = 0; p < 16; ++p) {
        const int c = p * 4 + cq;
        t[w][c] = f2bf(x[((size_t)((b * 64 + c) * 64) + h) * 64 + w]);
    }
    __syncthreads();
    const int w2 = tid >> 2, q = tid & 3;
    unsigned int pk[8];
    #pragma unroll
    for (int m = 0; m < 8; ++m)
        pk[m] = (unsigned int)t[w2][q * 16 + 2 * m] | ((unsigned int)t[w2][q * 16 + 2 * m + 1] << 16);
    uint4* dst = (uint4*)(xt + ((size_t)((b * 64 + h) * 64) + w2) * 64 + q * 16);
    dst[0] = uint4{pk[0], pk[1], pk[2], pk[3]};
    dst[1] = uint4{pk[4], pk[5], pk[6], pk[7]};
}

// ---------------- offset conv via MFMA, 1 wave per (b, h, quarter) ----------------
__global__ __launch_bounds__(64, 4) void k_offset_mfma(
    const unsigned short* __restrict__ xt, const unsigned short* __restrict__ WOF,
    const float* __restrict__ b_off, float* __restrict__ offs)
{
    const int l  = threadIdx.x;
    const int ml = l & 15;
    const int kg = l >> 4;
    const int q  = blockIdx.x & 3;
    const int h  = (blockIdx.x >> 2) & 63;
    const int b  = blockIdx.x >> 8;
    const int w  = q * 16 + ml;
    const unsigned short* xb = xt + (size_t)b * (IH * IW * CIN);

    const f32x4 fz = {0.f, 0.f, 0.f, 0.f};
    f32x4 acc0 = fz, acc1 = fz;

    #pragma unroll 1
    for (int s = 0; s < 18; ++s) {
        const int kk = s >> 1;
        const int ki = kk / 3, kj = kk - 3 * ki;
        const int c0 = (s & 1) * 32 + kg * 8;
        const int yy = h - PADC + ki;
        const int xx = w - PADC + kj;
        const bf16x8 b0 = *(const bf16x8*)(WOF + (size_t)(((s * 4 + kg) * 32 + ml) * 8));
        const bf16x8 b1 = *(const bf16x8*)(WOF + (size_t)(((s * 4 + kg) * 32 + 16 + ml) * 8));
        bf16x8 a = {0, 0, 0, 0, 0, 0, 0, 0};
        if (yy >= 0 && yy < IH && xx >= 0 && xx < IW)
            a = *(const bf16x8*)(xb + (size_t)((yy * IW + xx) * CIN) + c0);
        acc0 = __builtin_amdgcn_mfma_f32_16x16x32_bf16(a, b0, acc0, 0, 0, 0);
        acc1 = __builtin_amdgcn_mfma_f32_16x16x32_bf16(a, b1, acc1, 0, 0, 0);
    }
    #pragma unroll
    for (int nt = 0; nt < 2; ++nt) {
        const int oc = nt * 16 + ml;
        if (oc < NOFF) {
            const float bias = b_off[oc];
            const f32x4 av = nt ? acc1 : acc0;
            #pragma unroll
            for (int j = 0; j < 4; ++j) {
                const int wd = q * 16 + kg * 4 + j;
                offs[((size_t)(b * NOFF + oc) * IH + h) * IW + wd] = av[j] + bias;
            }
        }
    }
}

// ---------------- deformable conv via MFMA, 1 wave per (b, h, quarter) ----------------
__global__ __launch_bounds__(64, 4) void k_deform_mfma(
    const unsigned short* __restrict__ xt, const float* __restrict__ offs,
    const unsigned short* __restrict__ WDF, const float* __restrict__ b_def,
    unsigned short* __restrict__ feats_bf)
{
    const int l  = threadIdx.x;
    const int ml = l & 15;
    const int kg = l >> 4;
    const int q  = blockIdx.x & 3;
    const int h  = (blockIdx.x >> 2) & 63;
    const int b  = blockIdx.x >> 8;
    const int w  = q * 16 + ml;

    const unsigned short* xb = xt + (size_t)b * (IH * IW * CIN);

    const f32x4 fz = {0.f, 0.f, 0.f, 0.f};
    f32x4 acc[8];
    #pragma unroll
    for (int nt = 0; nt < 8; ++nt) acc[nt] = fz;

    #pragma unroll 1
    for (int kk = 0; kk < 9; ++kk) {
        const int ki = kk / 3, kj = kk - 3 * ki;
        const float dy = offs[((b * NOFF + 2 * kk) * IH + h) * IW + w];
        const float dx = offs[((b * NOFF + 2 * kk + 1) * IH + h) * IW + w];
        const float py = (float)(h - PADC + ki) + dy;
        const float px = (float)(w - PADC + kj) + dx;
        const float y0f = floorf(py), x0f = floorf(px);
        const float ly = py - y0f, lx = px - x0f;
        const int y0 = (int)y0f, x0 = (int)x0f;
        const float wy[2] = {1.f - ly, ly};
        const float wx[2] = {1.f - lx, lx};
        int   cidx[4];
        float cwgt[4];
        #pragma unroll
        for (int cy = 0; cy < 2; ++cy)
            #pragma unroll
            for (int cx = 0; cx < 2; ++cx) {
                const int yy = y0 + cy, xx = x0 + cx;
                const bool v = (yy >= 0) & (yy < IH) & (xx >= 0) & (xx < IW);
                cidx[cy * 2 + cx] = v ? ((yy * IW + xx) * CIN) : 0;
                cwgt[cy * 2 + cx] = v ? (wy[cy] * wx[cx]) : 0.f;
            }
        #pragma unroll
        for (int ks = 0; ks < 2; ++ks) {
            const int c0 = ks * 32 + kg * 8;
            uint4 cv[4];
            #pragma unroll
            for (int cp = 0; cp < 4; ++cp)
                cv[cp] = *(const uint4*)(xb + cidx[cp] + c0);
            bf16x8 bfr[8];
            #pragma unroll
            for (int nt = 0; nt < 8; ++nt)
                bfr[nt] = *(const bf16x8*)(WDF + ((size_t)((kk * 8 + ks * 4 + kg) * 128) + nt * 16 + ml) * 8);
            float sf[8] = {0.f, 0.f, 0.f, 0.f, 0.f, 0.f, 0.f, 0.f};
            #pragma unroll
            for (int cp = 0; cp < 4; ++cp) {
                const float wg = cwgt[cp];
                const unsigned int u0 = cv[cp].x, u1 = cv[cp].y, u2 = cv[cp].z, u3 = cv[cp].w;
                sf[0] += wg * __uint_as_float(u0 << 16);
                sf[1] += wg * __uint_as_float(u0 & 0xFFFF0000u);
                sf[2] += wg * __uint_as_float(u1 << 16);
                sf[3] += wg * __uint_as_float(u1 & 0xFFFF0000u);
                sf[4] += wg * __uint_as_float(u2 << 16);
                sf[5] += wg * __uint_as_float(u2 & 0xFFFF0000u);
                sf[6] += wg * __uint_as_float(u3 << 16);
                sf[7] += wg * __uint_as_float(u3 & 0xFFFF0000u);
            }
            union { unsigned short us[8]; bf16x8 v; } pa;
            #pragma unroll
            for (int j = 0; j < 8; ++j) pa.us[j] = f2bf(sf[j]);
            #pragma unroll
            for (int nt = 0; nt < 8; ++nt)
                acc[nt] = __builtin_amdgcn_mfma_f32_16x16x32_bf16(pa.v, bfr[nt], acc[nt], 0, 0, 0);
        }
    }
    #pragma unroll
    for (int nt = 0; nt < 8; ++nt) {
        const int o = nt * 16 + ml;
        const float bias = b_def[o];
        #pragma unroll
        for (int j = 0; j < 4; ++j) {
            const int wd = q * 16 + kg * 4 + j;
            feats_bf[((size_t)((b * IH + h) * IW) + wd) * COUT + o] = f2bf(acc[nt][j] + bias);
        }
    }
}

// ---------------- convT via MFMA + fused BN partial stats; y stored bf16 ----------------
__global__ __launch_bounds__(256) void k_convT_mfma(
    const unsigned short* __restrict__ feats_bf, const unsigned short* __restrict__ WB,
    unsigned short* __restrict__ y_bf, float* __restrict__ partials)
{
    __shared__ __align__(16) char smem[34048];   // 2*16896 rows / 4*8512 slabs (union)

    const int tid = threadIdx.x;
    const int l   = tid & 63;
    const int wv  = tid >> 6;
    const int ml  = l & 15;
    const int kg  = l >> 4;
    const int blk = blockIdx.x;
    const int oy  = blk % OYX;
    const int b   = blk / OYX;
    const int py  = oy & 1;
    const int ty  = oy >> 1;

    const int nrow = py ? 1 : 2;
    int iys[2];
    if (py == 0) { iys[0] = ty - 1; iys[1] = (ty <= 63) ? ty : -1; }
    else         { iys[0] = ty;     iys[1] = -1; }

    for (int r = 0; r < nrow; ++r) {
        char* dstbase = smem + r * 16896;
        const int iy = iys[r];
        if (iy < 0 || iy > 63) {
            for (int i = tid; i < 1056; i += 256)
                *(uint4*)(dstbase + i * 16) = uint4{0, 0, 0, 0};
        } else {
            const unsigned short* src = feats_bf + (size_t)(b * IH + iy) * (IW * COUT);
            for (int i = tid; i < 1024; i += 256) {
                const uint4 v = *(const uint4*)(src + i * 8);
                const int G = 16 + i;
                const int phys = G ^ ((G >> 4) & 7);
                *(uint4*)(dstbase + phys * 16) = v;
            }
            if (tid < 32) {
                const int G = (tid < 16) ? tid : (1024 + tid);
                const int phys = G ^ ((G >> 4) & 7);
                *(uint4*)(dstbase + phys * 16) = uint4{0, 0, 0, 0};
            }
        }
    }
    __syncthreads();

    const f32x4 fz = {0.f, 0.f, 0.f, 0.f};
    f32x4 acc0[5][2], acc1[4][2];
    #pragma unroll
    for (int m = 0; m < 5; ++m) { acc0[m][0] = fz; acc0[m][1] = fz; }
    #pragma unroll
    for (int m = 0; m < 4; ++m) { acc1[m][0] = fz; acc1[m][1] = fz; }

    const int n0   = wv * 32;
    const int nK0  = py ? 8 : 16;
    const int nK1  = py ? 4 : 8;
    const unsigned short* segG0 = WB + (py ? 65536 : 0);
    const unsigned short* segG1 = WB + (py ? 131072 : 98304);

    for (int ks = 0; ks < nK0; ++ks) {
        const int kk   = ks * 32 + kg * 8;
        const int slot = kk >> 8;
        const int kb   = (kk & 255) >> 3;
        const bf16x8 b0 = *(const bf16x8*)(segG0 + ((ks * 4 + kg) * 128 + n0 + ml) * 8);
        const bf16x8 b1 = *(const bf16x8*)(segG0 + ((ks * 4 + kg) * 128 + n0 + 16 + ml) * 8);
        #pragma unroll
        for (int mt = 0; mt < 5; ++mt) {
            int tx = mt * 16 + ml; if (tx > 64) tx = 64;
            const int G = tx * 16 + kb;
            const int phys = G ^ ((G >> 4) & 7);
            const bf16x8 a = *(const bf16x8*)(smem + slot * 16896 + phys * 16);
            acc0[mt][0] = __builtin_amdgcn_mfma_f32_16x16x32_bf16(a, b0, acc0[mt][0], 0, 0, 0);
            acc0[mt][1] = __builtin_amdgcn_mfma_f32_16x16x32_bf16(a, b1, acc0[mt][1], 0, 0, 0);
        }
    }
    for (int ks = 0; ks < nK1; ++ks) {
        const int kk   = ks * 32 + kg * 8;
        const int slot = kk >> 7;
        const int kb   = (kk & 127) >> 3;
        const bf16x8 b0 = *(const bf16x8*)(segG1 + ((ks * 4 + kg) * 128 + n0 + ml) * 8);
        const bf16x8 b1 = *(const bf16x8*)(segG1 + ((ks * 4 + kg) * 128 + n0 + 16 + ml) * 8);
        #pragma unroll
        for (int mt = 0; mt < 4; ++mt) {
            const int tx = mt * 16 + ml;
            const int G = 16 + tx * 16 + kb;
            const int phys = G ^ ((G >> 4) & 7);
            const bf16x8 a = *(const bf16x8*)(smem + slot * 16896 + phys * 16);
            acc1[mt][0] = __builtin_amdgcn_mfma_f32_16x16x32_bf16(a, b0, acc1[mt][0], 0, 0, 0);
            acc1[mt][1] = __builtin_amdgcn_mfma_f32_16x16x32_bf16(a, b1, acc1[mt][1], 0, 0, 0);
        }
    }

    __syncthreads();
    float* slab = (float*)smem + wv * 2128;   // [16 co][133 ox]
    const int rrow = kg * 4;
    #pragma unroll
    for (int nt = 0; nt < 2; ++nt) {
        #pragma unroll
        for (int mt = 0; mt < 5; ++mt) {
            #pragma unroll
            for (int j = 0; j < 4; ++j) {
                const int tx = mt * 16 + rrow + j;
                if (tx <= 64) slab[ml * 133 + 2 * tx] = acc0[mt][nt][j];
            }
        }
        #pragma unroll
        for (int mt = 0; mt < 4; ++mt) {
            #pragma unroll
            for (int j = 0; j < 4; ++j) {
                const int tx = mt * 16 + rrow + j;
                slab[ml * 133 + 2 * tx + 1] = acc1[mt][nt][j];
            }
        }
        __syncthreads();
        // store y as bf16 (no bias — cancels in BN)
        #pragma unroll
        for (int r2 = 0; r2 < 16; ++r2) {
            const int co = n0 + nt * 16 + r2;
            unsigned short* drow = y_bf + ((size_t)(b * COUT + co) * OYX + oy) * OYX;
            drow[l]      = f2bf(slab[r2 * 133 + l]);
            drow[64 + l] = f2bf(slab[r2 * 133 + 64 + l]);
            if (l == 0) drow[128] = f2bf(slab[r2 * 133 + 128]);
        }
        // fused BN partials from f32 slab: lane-per-co-row column sums, 4-lane reduce
        {
            const int r = ml;          // co row 0..15
            const int g = kg;          // column group 0..3
            float s = 0.f, q = 0.f;
            #pragma unroll
            for (int t = 0; t < 33; ++t) {
                const int cx = g + 4 * t;
                if (cx < 129) {
                    const float v = slab[r * 133 + cx];
                    s += v; q += v * v;
                }
            }
            s += __shfl_xor(s, 16, 64); q += __shfl_xor(q, 16, 64);
            s += __shfl_xor(s, 32, 64); q += __shfl_xor(q, 32, 64);
            if (kg == 0) {
                float* pp = partials + ((size_t)blk * COUT + n0 + nt * 16 + ml) * 2;
                pp[0] = s; pp[1] = q;
            }
        }
        __syncthreads();
    }
}

// ---------------- BN finalize: reduce per-block partials ----------------
__global__ __launch_bounds__(256) void k_bn_final(const float* __restrict__ partials,
                                                  float* __restrict__ stats)
{
    const int c = blockIdx.x;      // 128
    const int tid = threadIdx.x;
    float s = 0.f, q = 0.f;
    for (int i = tid; i < NBLK_CT; i += 256) {
        const float* pp = partials + ((size_t)i * COUT + c) * 2;
        s += pp[0]; q += pp[1];
    }
    __shared__ float rs[256], rq[256];
    rs[tid] = s; rq[tid] = q;
    __syncthreads();
    for (int off = 128; off > 0; off >>= 1) {
        if (tid < off) { rs[tid] += rs[tid + off]; rq[tid] += rq[tid + off]; }
        __syncthreads();
    }
    if (tid == 0) {
        const float n = (float)(NB * SPO);
        const float mean = rs[0] / n;
        const float var  = rq[0] / n - mean * mean;
        stats[c] = mean;
        stats[COUT + c] = rsqrtf(var + BNEPS);
    }
}

// ---------------- BN apply + ReLU: read bf16 y, write f32 d_out ----------------
__global__ void k_bn_apply(const unsigned short* __restrict__ y_bf, float* __restrict__ y,
                           const float* __restrict__ stats,
                           const float* __restrict__ gamma, const float* __restrict__ beta)
{
    const int i = blockIdx.x * 256 + threadIdx.x;
    const int c = (i / SPO) & (COUT - 1);
    const float mean = stats[c], rstd = stats[COUT + c];
    float v = bf2f(y_bf[i]);
    v = (v - mean) * rstd * gamma[c] + beta[c];
    y[i] = fmaxf(v, 0.f);
}

extern "C" void kernel_launch(void* const* d_in, const int* in_sizes, int n_in,
                              void* d_out, int out_size, void* d_ws, size_t ws_size,
                              hipStream_t stream)
{
    const float* x     = (const float*)d_in[0];
    const float* w_off = (const float*)d_in[1];
    const float* b_off = (const float*)d_in[2];
    const float* w_def = (const float*)d_in[3];
    const float* b_def = (const float*)d_in[4];
    const float* w_up  = (const float*)d_in[5];
    const float* b_up  = (const float*)d_in[6];  (void)b_up;  // cancels in BN
    const float* gamma = (const float*)d_in[7];
    const float* beta  = (const float*)d_in[8];
    float* y = (float*)d_out;

    float* ws       = (float*)d_ws;
    float* offs     = ws;                     // 1,179,648 f32
    float* stats    = offs + 1179648;         //       256 f32
    float* partials = stats + 256;            //   528,384 f32
    unsigned short* xt       = (unsigned short*)(partials + 528384);  //  4,194,304 bf16
    unsigned short* WDF      = xt + 4194304;                          //     73,728 bf16
    unsigned short* feats_bf = WDF + 73728;                           //  8,388,608 bf16
    unsigned short* WB       = feats_bf + 8388608;                    //    147,456 bf16
    unsigned short* WOF      = WB + 147456;                           //     18,432 bf16
    unsigned short* y_bf     = WOF + 18432;                           // 34,080,768 bf16

    k_prep        <<<dim3(936),    dim3(256), 0, stream>>>(w_def, w_up, w_off, WDF, WB, WOF);
    k_xt          <<<dim3(1024),   dim3(256), 0, stream>>>(x, xt);
    k_offset_mfma <<<dim3(4096),   dim3(64),  0, stream>>>(xt, WOF, b_off, offs);
    k_deform_mfma <<<dim3(4096),   dim3(64),  0, stream>>>(xt, offs, WDF, b_def, feats_bf);
    k_convT_mfma  <<<dim3(NBLK_CT),dim3(256), 0, stream>>>(feats_bf, WB, y_bf, partials);
    k_bn_final    <<<dim3(128),    dim3(256), 0, stream>>>(partials, stats);
    k_bn_apply    <<<dim3(133128), dim3(256), 0, stream>>>(y_bf, y, stats, gamma, beta);
}

// Round 8
// 174.876 us; speedup vs baseline: 9.3153x; 1.1346x over previous
//
#include <hip/hip_runtime.h>
#include <math.h>

#define PADC 1
#define CIN  64
#define COUT 128
#define IH   64
#define IW   64
#define NB   16
#define OYX  129
#define OXP  136            // padded y_bf row (16B-aligned rows)
#define NOFF 18
#define SPO  (OYX * OYX)   // 16641
#define BNEPS 1e-5f
#define NBLK_CT (NB * 65)  // 1040 paired convT blocks

typedef __attribute__((ext_vector_type(8))) short bf16x8;
typedef __attribute__((ext_vector_type(4))) float f32x4;

static __device__ __forceinline__ unsigned short f2bf(float f) {
    unsigned int b = __float_as_uint(f);
    unsigned int r = (b + 0x7FFFu + ((b >> 16) & 1u)) >> 16;   // RNE
    return (unsigned short)r;
}
static __device__ __forceinline__ float bf2f(unsigned short u) {
    return __uint_as_float((unsigned int)u << 16);
}

// ---------------- weight prep ----------------
__global__ void k_prep(const float* __restrict__ w_def, const float* __restrict__ w_up,
                       const float* __restrict__ w_off,
                       unsigned short* __restrict__ WDF, unsigned short* __restrict__ WB,
                       unsigned short* __restrict__ WOF)
{
    int idx = blockIdx.x * 256 + threadIdx.x;
    if (idx < 73728) {
        const int j = idx & 7;
        const int n = (idx >> 3) & 127;
        const int g = idx >> 10;            // 0..71 = kk*8 + ks*4 + kg
        const int kg = g & 3, ks = (g >> 2) & 1, kk = g >> 3;
        const int c = ks * 32 + kg * 8 + j;
        WDF[idx] = f2bf(w_def[(n * CIN + c) * 9 + kk]);
    }
    const int i2 = idx - 73728;
    if (i2 >= 0 && i2 < 147456) {
        const int j = i2 & 7;
        const int n = (i2 >> 3) & 127;
        int ky, kx, ci;
        if (i2 < 65536) {
            const int k = (i2 >> 10) * 8 + j;            // 0..511
            ky = (k >> 8) ? 0 : 2;
            kx = ((k >> 7) & 1) ? 0 : 2;
            ci = k & 127;
        } else if (i2 < 98304) {
            const int k = ((i2 - 65536) >> 10) * 8 + j;  // 0..255
            ky = 1;
            kx = (k >> 7) ? 0 : 2;
            ci = k & 127;
        } else if (i2 < 131072) {
            const int k = ((i2 - 98304) >> 10) * 8 + j;  // 0..255
            ky = (k >> 7) ? 0 : 2;
            kx = 1;
            ci = k & 127;
        } else {
            const int k = ((i2 - 131072) >> 10) * 8 + j; // 0..127
            ky = 1; kx = 1;
            ci = k & 127;
        }
        WB[i2] = f2bf(w_up[((ci * COUT + n) * 3 + ky) * 3 + kx]);
    }
    const int i3 = idx - 221184;
    if (i3 >= 0 && i3 < 18432) {
        const int j = i3 & 7;
        const int n = (i3 >> 3) & 31;
        const int g = i3 >> 8;              // 0..71 = s*4 + kg
        const int kg = g & 3, s = g >> 2;
        const int c  = (s & 1) * 32 + kg * 8 + j;
        const int kk = s >> 1;
        const int ki = kk / 3, kj = kk - 3 * ki;
        WOF[i3] = (n < NOFF) ? f2bf(w_off[((n * CIN + c) * 3 + ki) * 3 + kj]) : (unsigned short)0;
    }
}

// ---------------- x transpose to channel-last bf16: xt[b][h][w][c] ----------------
__global__ __launch_bounds__(256) void k_xt(const float* __restrict__ x, unsigned short* __restrict__ xt)
{
    __shared__ unsigned short t[64][66];
    const int tid = threadIdx.x;
    const int h = blockIdx.x & 63, b = blockIdx.x >> 6;
    const int w = tid & 63, cq = tid >> 6;
    #pragma unroll
    for (int p = 0; p < 16; ++p) {
        const int c = p * 4 + cq;
        t[w][c] = f2bf(x[((size_t)((b * 64 + c) * 64) + h) * 64 + w]);
    }
    __syncthreads();
    const int w2 = tid >> 2, q = tid & 3;
    unsigned int pk[8];
    #pragma unroll
    for (int m = 0; m < 8; ++m)
        pk[m] = (unsigned int)t[w2][q * 16 + 2 * m] | ((unsigned int)t[w2][q * 16 + 2 * m + 1] << 16);
    uint4* dst = (uint4*)(xt + ((size_t)((b * 64 + h) * 64) + w2) * 64 + q * 16);
    dst[0] = uint4{pk[0], pk[1], pk[2], pk[3]};
    dst[1] = uint4{pk[4], pk[5], pk[6], pk[7]};
}

// ---------------- offset conv via MFMA, 1 wave per (b, h, quarter) ----------------
__global__ __launch_bounds__(64, 4) void k_offset_mfma(
    const unsigned short* __restrict__ xt, const unsigned short* __restrict__ WOF,
    const float* __restrict__ b_off, float* __restrict__ offs)
{
    const int l  = threadIdx.x;
    const int ml = l & 15;
    const int kg = l >> 4;
    const int q  = blockIdx.x & 3;
    const int h  = (blockIdx.x >> 2) & 63;
    const int b  = blockIdx.x >> 8;
    const int w  = q * 16 + ml;
    const unsigned short* xb = xt + (size_t)b * (IH * IW * CIN);

    const f32x4 fz = {0.f, 0.f, 0.f, 0.f};
    f32x4 acc0 = fz, acc1 = fz;

    #pragma unroll 1
    for (int s = 0; s < 18; ++s) {
        const int kk = s >> 1;
        const int ki = kk / 3, kj = kk - 3 * ki;
        const int c0 = (s & 1) * 32 + kg * 8;
        const int yy = h - PADC + ki;
        const int xx = w - PADC + kj;
        const bf16x8 b0 = *(const bf16x8*)(WOF + (size_t)(((s * 4 + kg) * 32 + ml) * 8));
        const bf16x8 b1 = *(const bf16x8*)(WOF + (size_t)(((s * 4 + kg) * 32 + 16 + ml) * 8));
        bf16x8 a = {0, 0, 0, 0, 0, 0, 0, 0};
        if (yy >= 0 && yy < IH && xx >= 0 && xx < IW)
            a = *(const bf16x8*)(xb + (size_t)((yy * IW + xx) * CIN) + c0);
        acc0 = __builtin_amdgcn_mfma_f32_16x16x32_bf16(a, b0, acc0, 0, 0, 0);
        acc1 = __builtin_amdgcn_mfma_f32_16x16x32_bf16(a, b1, acc1, 0, 0, 0);
    }
    #pragma unroll
    for (int nt = 0; nt < 2; ++nt) {
        const int oc = nt * 16 + ml;
        if (oc < NOFF) {
            const float bias = b_off[oc];
            const f32x4 av = nt ? acc1 : acc0;
            #pragma unroll
            for (int j = 0; j < 4; ++j) {
                const int wd = q * 16 + kg * 4 + j;
                offs[((size_t)(b * NOFF + oc) * IH + h) * IW + wd] = av[j] + bias;
            }
        }
    }
}

// ---------------- deformable conv via MFMA, 1 wave per (b, h, quarter) ----------------
__global__ __launch_bounds__(64, 4) void k_deform_mfma(
    const unsigned short* __restrict__ xt, const float* __restrict__ offs,
    const unsigned short* __restrict__ WDF, const float* __restrict__ b_def,
    unsigned short* __restrict__ feats_bf)
{
    const int l  = threadIdx.x;
    const int ml = l & 15;
    const int kg = l >> 4;
    const int q  = blockIdx.x & 3;
    const int h  = (blockIdx.x >> 2) & 63;
    const int b  = blockIdx.x >> 8;
    const int w  = q * 16 + ml;

    const unsigned short* xb = xt + (size_t)b * (IH * IW * CIN);

    const f32x4 fz = {0.f, 0.f, 0.f, 0.f};
    f32x4 acc[8];
    #pragma unroll
    for (int nt = 0; nt < 8; ++nt) acc[nt] = fz;

    #pragma unroll 1
    for (int kk = 0; kk < 9; ++kk) {
        const int ki = kk / 3, kj = kk - 3 * ki;
        const float dy = offs[((b * NOFF + 2 * kk) * IH + h) * IW + w];
        const float dx = offs[((b * NOFF + 2 * kk + 1) * IH + h) * IW + w];
        const float py = (float)(h - PADC + ki) + dy;
        const float px = (float)(w - PADC + kj) + dx;
        const float y0f = floorf(py), x0f = floorf(px);
        const float ly = py - y0f, lx = px - x0f;
        const int y0 = (int)y0f, x0 = (int)x0f;
        const float wy[2] = {1.f - ly, ly};
        const float wx[2] = {1.f - lx, lx};
        int   cidx[4];
        float cwgt[4];
        #pragma unroll
        for (int cy = 0; cy < 2; ++cy)
            #pragma unroll
            for (int cx = 0; cx < 2; ++cx) {
                const int yy = y0 + cy, xx = x0 + cx;
                const bool v = (yy >= 0) & (yy < IH) & (xx >= 0) & (xx < IW);
                cidx[cy * 2 + cx] = v ? ((yy * IW + xx) * CIN) : 0;
                cwgt[cy * 2 + cx] = v ? (wy[cy] * wx[cx]) : 0.f;
            }
        #pragma unroll
        for (int ks = 0; ks < 2; ++ks) {
            const int c0 = ks * 32 + kg * 8;
            uint4 cv[4];
            #pragma unroll
            for (int cp = 0; cp < 4; ++cp)
                cv[cp] = *(const uint4*)(xb + cidx[cp] + c0);
            bf16x8 bfr[8];
            #pragma unroll
            for (int nt = 0; nt < 8; ++nt)
                bfr[nt] = *(const bf16x8*)(WDF + ((size_t)((kk * 8 + ks * 4 + kg) * 128) + nt * 16 + ml) * 8);
            float sf[8] = {0.f, 0.f, 0.f, 0.f, 0.f, 0.f, 0.f, 0.f};
            #pragma unroll
            for (int cp = 0; cp < 4; ++cp) {
                const float wg = cwgt[cp];
                const unsigned int u0 = cv[cp].x, u1 = cv[cp].y, u2 = cv[cp].z, u3 = cv[cp].w;
                sf[0] += wg * __uint_as_float(u0 << 16);
                sf[1] += wg * __uint_as_float(u0 & 0xFFFF0000u);
                sf[2] += wg * __uint_as_float(u1 << 16);
                sf[3] += wg * __uint_as_float(u1 & 0xFFFF0000u);
                sf[4] += wg * __uint_as_float(u2 << 16);
                sf[5] += wg * __uint_as_float(u2 & 0xFFFF0000u);
                sf[6] += wg * __uint_as_float(u3 << 16);
                sf[7] += wg * __uint_as_float(u3 & 0xFFFF0000u);
            }
            union { unsigned short us[8]; bf16x8 v; } pa;
            #pragma unroll
            for (int j = 0; j < 8; ++j) pa.us[j] = f2bf(sf[j]);
            #pragma unroll
            for (int nt = 0; nt < 8; ++nt)
                acc[nt] = __builtin_amdgcn_mfma_f32_16x16x32_bf16(pa.v, bfr[nt], acc[nt], 0, 0, 0);
        }
    }
    #pragma unroll
    for (int nt = 0; nt < 8; ++nt) {
        const int o = nt * 16 + ml;
        const float bias = b_def[o];
        #pragma unroll
        for (int j = 0; j < 4; ++j) {
            const int wd = q * 16 + kg * 4 + j;
            feats_bf[((size_t)((b * IH + h) * IW) + wd) * COUT + o] = f2bf(acc[nt][j] + bias);
        }
    }
}

// ---------------- convT via MFMA: paired oy rows, slab-free epilogue ----------------
// block = (b, t), t in [0,64]: computes oy=2t (even) and oy=2t+1 (odd, skipped at t=64).
// Stages input rows t-1 (slot0) and t (slot1) once; shares across both oy rows.
// y_bf rows padded to OXP=136 elems -> packed u32/uint4 direct stores from acc regs.
__global__ __launch_bounds__(256) void k_convT_mfma(
    const unsigned short* __restrict__ feats_bf, const unsigned short* __restrict__ WB,
    unsigned short* __restrict__ y_bf, float* __restrict__ partials)
{
    __shared__ __align__(16) char smem[33792];   // 2 slots x 16896

    const int tid = threadIdx.x;
    const int l   = tid & 63;
    const int wv  = tid >> 6;
    const int ml  = l & 15;
    const int kg  = l >> 4;
    const int blk = blockIdx.x;
    const int t   = blk % 65;
    const int b   = blk / 65;

    // ---- stage rows t-1 -> slot0, t -> slot1 ----
    for (int r = 0; r < 2; ++r) {
        char* dstbase = smem + r * 16896;
        const int iy = t - 1 + r;
        if (iy < 0 || iy > 63) {
            for (int i = tid; i < 1056; i += 256)
                *(uint4*)(dstbase + i * 16) = uint4{0, 0, 0, 0};
        } else {
            const unsigned short* src = feats_bf + (size_t)(b * IH + iy) * (IW * COUT);
            for (int i = tid; i < 1024; i += 256) {
                const uint4 v = *(const uint4*)(src + i * 8);
                const int G = 16 + i;
                const int phys = G ^ ((G >> 4) & 7);
                *(uint4*)(dstbase + phys * 16) = v;
            }
            if (tid < 32) {
                const int G = (tid < 16) ? tid : (1024 + tid);
                const int phys = G ^ ((G >> 4) & 7);
                *(uint4*)(dstbase + phys * 16) = uint4{0, 0, 0, 0};
            }
        }
    }
    __syncthreads();

    const int n0 = wv * 32;
    const f32x4 fz = {0.f, 0.f, 0.f, 0.f};
    float sacc[2] = {0.f, 0.f}, qacc[2] = {0.f, 0.f};

    #pragma unroll 1
    for (int p = 0; p < 2; ++p) {                 // p=0: oy=2t, p=1: oy=2t+1
        if (p == 1 && t == 64) break;
        const int oy = 2 * t + p;
        const unsigned short* segG0 = WB + (p ? 65536 : 0);
        const unsigned short* segG1 = WB + (p ? 131072 : 98304);
        const int nK0 = p ? 8 : 16;
        const int nK1 = p ? 4 : 8;

        f32x4 acc0[5][2], acc1[4][2];
        #pragma unroll
        for (int m = 0; m < 5; ++m) { acc0[m][0] = fz; acc0[m][1] = fz; }
        #pragma unroll
        for (int m = 0; m < 4; ++m) { acc1[m][0] = fz; acc1[m][1] = fz; }

        // G0: even ox (2-pixel K-run)
        for (int ks = 0; ks < nK0; ++ks) {
            const int kk   = ks * 32 + kg * 8;
            const int slot = p ? 1 : (kk >> 8);   // even: k<256 ky=2 -> row t-1
            const int kb   = (kk & 255) >> 3;
            const bf16x8 b0 = *(const bf16x8*)(segG0 + ((ks * 4 + kg) * 128 + n0 + ml) * 8);
            const bf16x8 b1 = *(const bf16x8*)(segG0 + ((ks * 4 + kg) * 128 + n0 + 16 + ml) * 8);
            #pragma unroll
            for (int mt = 0; mt < 5; ++mt) {
                int tx = mt * 16 + ml; if (tx > 64) tx = 64;
                const int G = tx * 16 + kb;
                const int phys = G ^ ((G >> 4) & 7);
                const bf16x8 a = *(const bf16x8*)(smem + slot * 16896 + phys * 16);
                acc0[mt][0] = __builtin_amdgcn_mfma_f32_16x16x32_bf16(a, b0, acc0[mt][0], 0, 0, 0);
                acc0[mt][1] = __builtin_amdgcn_mfma_f32_16x16x32_bf16(a, b1, acc0[mt][1], 0, 0, 0);
            }
        }
        // G1: odd ox
        for (int ks = 0; ks < nK1; ++ks) {
            const int kk   = ks * 32 + kg * 8;
            const int slot = p ? 1 : (kk >> 7);
            const int kb   = (kk & 127) >> 3;
            const bf16x8 b0 = *(const bf16x8*)(segG1 + ((ks * 4 + kg) * 128 + n0 + ml) * 8);
            const bf16x8 b1 = *(const bf16x8*)(segG1 + ((ks * 4 + kg) * 128 + n0 + 16 + ml) * 8);
            #pragma unroll
            for (int mt = 0; mt < 4; ++mt) {
                const int tx = mt * 16 + ml;
                const int G = 16 + tx * 16 + kb;
                const int phys = G ^ ((G >> 4) & 7);
                const bf16x8 a = *(const bf16x8*)(smem + slot * 16896 + phys * 16);
                acc1[mt][0] = __builtin_amdgcn_mfma_f32_16x16x32_bf16(a, b0, acc1[mt][0], 0, 0, 0);
                acc1[mt][1] = __builtin_amdgcn_mfma_f32_16x16x32_bf16(a, b1, acc1[mt][1], 0, 0, 0);
            }
        }

        // direct packed stores + register stats (D: row tx = 16mt+4kg+j, col co = n0+16nt+ml)
        #pragma unroll
        for (int nt = 0; nt < 2; ++nt) {
            const int co = n0 + nt * 16 + ml;
            unsigned int* drow32 = (unsigned int*)(y_bf + ((size_t)(b * COUT + co) * OYX + oy) * OXP);
            #pragma unroll
            for (int mt = 0; mt < 4; ++mt) {
                unsigned int pk[4];
                #pragma unroll
                for (int j = 0; j < 4; ++j) {
                    const float ve = acc0[mt][nt][j];
                    const float vo = acc1[mt][nt][j];
                    pk[j] = (unsigned int)f2bf(ve) | ((unsigned int)f2bf(vo) << 16);
                    sacc[nt] += ve + vo;
                    qacc[nt] += ve * ve + vo * vo;
                }
                *(uint4*)(drow32 + mt * 16 + kg * 4) = uint4{pk[0], pk[1], pk[2], pk[3]};
            }
            if (kg == 0) {                       // edge ox=128 (tx=64)
                const float ve = acc0[4][nt][0];
                drow32[64] = (unsigned int)f2bf(ve);
                sacc[nt] += ve;
                qacc[nt] += ve * ve;
            }
        }
    }

    // reduce stats across the 4 lanes sharing each co, write per-block partials
    #pragma unroll
    for (int nt = 0; nt < 2; ++nt) {
        float ss = sacc[nt], qq = qacc[nt];
        ss += __shfl_xor(ss, 16, 64); qq += __shfl_xor(qq, 16, 64);
        ss += __shfl_xor(ss, 32, 64); qq += __shfl_xor(qq, 32, 64);
        if (kg == 0) {
            float* pp = partials + ((size_t)blk * COUT + n0 + nt * 16 + ml) * 2;
            pp[0] = ss; pp[1] = qq;
        }
    }
}

// ---------------- BN finalize: reduce per-block partials ----------------
__global__ __launch_bounds__(256) void k_bn_final(const float* __restrict__ partials,
                                                  float* __restrict__ stats)
{
    const int c = blockIdx.x;      // 128
    const int tid = threadIdx.x;
    float s = 0.f, q = 0.f;
    for (int i = tid; i < NBLK_CT; i += 256) {
        const float* pp = partials + ((size_t)i * COUT + c) * 2;
        s += pp[0]; q += pp[1];
    }
    __shared__ float rs[256], rq[256];
    rs[tid] = s; rq[tid] = q;
    __syncthreads();
    for (int off = 128; off > 0; off >>= 1) {
        if (tid < off) { rs[tid] += rs[tid + off]; rq[tid] += rq[tid + off]; }
        __syncthreads();
    }
    if (tid == 0) {
        const float n = (float)(NB * SPO);
        const float mean = rs[0] / n;
        const float var  = rq[0] / n - mean * mean;
        stats[c] = mean;
        stats[COUT + c] = rsqrtf(var + BNEPS);
    }
}

// ---------------- BN apply + ReLU: 8-wide bf16 read (padded rows), f32 write ----------------
// thread v: row rid = v/17, chunk c = v%17; chunks 0..15 = 8 ox each, chunk 16 = ox 128.
__global__ __launch_bounds__(256) void k_bn_apply(
    const unsigned short* __restrict__ y_bf, float* __restrict__ y,
    const float* __restrict__ stats,
    const float* __restrict__ gamma, const float* __restrict__ beta)
{
    const int v = blockIdx.x * 256 + threadIdx.x;   // exact: 264192*17 = 4,491,264
    const int rid = v / 17;
    const int c   = v - rid * 17;
    const int co  = (rid / OYX) & (COUT - 1);
    const float mean = stats[co], rstd = stats[COUT + co];
    const float ga = gamma[co], be = beta[co];
    const int ox0 = c * 8;

    const uint4 u = *(const uint4*)(y_bf + (size_t)rid * OXP + ox0);
    const unsigned int uu[4] = {u.x, u.y, u.z, u.w};
    float* dst = y + (size_t)rid * OYX + ox0;
    const int nv = (c < 16) ? 8 : 1;
    #pragma unroll
    for (int m = 0; m < 4; ++m) {
        float v0 = bf2f((unsigned short)(uu[m] & 0xFFFFu));
        float v1 = bf2f((unsigned short)(uu[m] >> 16));
        v0 = fmaxf((v0 - mean) * rstd * ga + be, 0.f);
        v1 = fmaxf((v1 - mean) * rstd * ga + be, 0.f);
        if (2 * m < nv)     dst[2 * m]     = v0;
        if (2 * m + 1 < nv) dst[2 * m + 1] = v1;
    }
}

extern "C" void kernel_launch(void* const* d_in, const int* in_sizes, int n_in,
                              void* d_out, int out_size, void* d_ws, size_t ws_size,
                              hipStream_t stream)
{
    const float* x     = (const float*)d_in[0];
    const float* w_off = (const float*)d_in[1];
    const float* b_off = (const float*)d_in[2];
    const float* w_def = (const float*)d_in[3];
    const float* b_def = (const float*)d_in[4];
    const float* w_up  = (const float*)d_in[5];
    const float* b_up  = (const float*)d_in[6];  (void)b_up;  // cancels in BN
    const float* gamma = (const float*)d_in[7];
    const float* beta  = (const float*)d_in[8];
    float* y = (float*)d_out;

    float* ws       = (float*)d_ws;
    float* offs     = ws;                     // 1,179,648 f32
    float* stats    = offs + 1179648;         //       256 f32
    float* partials = stats + 256;            //   266,240 f32 (1040*128*2)
    unsigned short* xt       = (unsigned short*)(partials + 528384);  //  4,194,304 bf16
    unsigned short* WDF      = xt + 4194304;                          //     73,728 bf16
    unsigned short* feats_bf = WDF + 73728;                           //  8,388,608 bf16
    unsigned short* WB       = feats_bf + 8388608;                    //    147,456 bf16
    unsigned short* WOF      = WB + 147456;                           //     18,432 bf16
    unsigned short* y_bf     = WOF + 18432;                           // 35,930,112 bf16 (padded rows)

    k_prep        <<<dim3(936),    dim3(256), 0, stream>>>(w_def, w_up, w_off, WDF, WB, WOF);
    k_xt          <<<dim3(1024),   dim3(256), 0, stream>>>(x, xt);
    k_offset_mfma <<<dim3(4096),   dim3(64),  0, stream>>>(xt, WOF, b_off, offs);
    k_deform_mfma <<<dim3(4096),   dim3(64),  0, stream>>>(xt, offs, WDF, b_def, feats_bf);
    k_convT_mfma  <<<dim3(NBLK_CT),dim3(256), 0, stream>>>(feats_bf, WB, y_bf, partials);
    k_bn_final    <<<dim3(128),    dim3(256), 0, stream>>>(partials, stats);
    k_bn_apply    <<<dim3(17544),  dim3(256), 0, stream>>>(y_bf, y, stats, gamma, beta);
}